// Round 1
// baseline (1938.170 us; speedup 1.0000x reference)
//
#include <hip/hip_runtime.h>

#define NPTS   65536
#define NB     2048
#define DIMX   256
#define HIDN   512
#define MAXNN  64
#define MIDK   288
#define MIDV   384
#define MIDD   384
#define MIDS   256

// ---------------- helpers ----------------
__device__ __forceinline__ float mishf(float x) {
    float sp = (x > 20.f) ? x : log1pf(expf(x));
    return x * tanhf(sp);
}
__device__ __forceinline__ unsigned short f2bf(float f) {
    unsigned u = __float_as_uint(f);
    u += 0x7fffu + ((u >> 16) & 1u);
    return (unsigned short)(u >> 16);
}
__device__ __forceinline__ float bf2f(unsigned short h) {
    return __uint_as_float(((unsigned)h) << 16);
}

// ---------------- small kernels ----------------

// starts[b] = lower_bound(batch, b), b in [0, 2048]; also zero maxmag.
__global__ __launch_bounds__(256)
void k_starts(const int* __restrict__ batch, int* __restrict__ starts,
              unsigned int* __restrict__ maxmag)
{
    int b = blockIdx.x * blockDim.x + threadIdx.x;
    if (b == 0) *maxmag = 0u;
    if (b <= NB) {
        int lo = 0, hi = NPTS;
        while (lo < hi) { int mid = (lo + hi) >> 1; if (batch[mid] < b) lo = mid + 1; else hi = mid; }
        starts[b] = lo;
    }
}

// mag[i] = |x[i,:]@rW + rb| (f64 accumulate), plus global max via atomicMax on bits.
__global__ __launch_bounds__(256)
void k_mag(const float* __restrict__ x, const float* __restrict__ rW,
           const float* __restrict__ rb, float* __restrict__ mag,
           unsigned int* __restrict__ maxmag)
{
    const int lane = threadIdx.x & 63;
    const int wave = threadIdx.x >> 6;
    const int gw = blockIdx.x * 4 + wave;   // 4096 waves total
    float4 wv = *(const float4*)(rW + lane * 4);
    float bias = rb[0];
    float lmax = 0.f;
    for (int pt = gw; pt < NPTS; pt += 4096) {
        float4 xv = *(const float4*)(x + (size_t)pt * DIMX + lane * 4);
        double d = (double)xv.x * wv.x + (double)xv.y * wv.y
                 + (double)xv.z * wv.z + (double)xv.w * wv.w;
        #pragma unroll
        for (int o = 32; o > 0; o >>= 1) d += __shfl_xor(d, o);
        float s = fabsf((float)(d + (double)bias));
        if (lane == 0) mag[pt] = s;
        lmax = fmaxf(lmax, s);
    }
    __shared__ float wm[4];
    if (lane == 0) wm[wave] = lmax;
    __syncthreads();
    if (threadIdx.x == 0) {
        float m = fmaxf(fmaxf(wm[0], wm[1]), fmaxf(wm[2], wm[3]));
        atomicMax(maxmag, __float_as_uint(m));
    }
}

// key_idx[i] = rank of point i within its batch segment by stable f32 key b*M+mag.
__global__ __launch_bounds__(256)
void k_rank(const int* __restrict__ batch, const int* __restrict__ starts,
            const float* __restrict__ mag, const unsigned int* __restrict__ maxmag,
            int* __restrict__ kidx)
{
    int i = blockIdx.x * 256 + threadIdx.x;
    if (i >= NPTS) return;
    int b = batch[i];
    int s = starts[b], e = starts[b + 1];
    float M = __uint_as_float(*maxmag);
    float kb = __fmul_rn((float)b, M);
    float ki = __fadd_rn(kb, mag[i]);
    int r = 0;
    for (int j = s; j < e; ++j) {
        float kj = __fadd_rn(kb, mag[j]);
        r += (kj < ki) || (kj == ki && j < i);
    }
    kidx[i] = (r < MAXNN) ? r : MAXNN;
}

// Build key table: row = blockIdx.x. in = W1[row,:]+b1 (or b1 alone for the
// zero-one-hot row, row >= n_w1_rows), then LN, mish, @W2 + b2 -> tbl[row, 0..511].
__global__ __launch_bounds__(512)
void k_table(const float* __restrict__ W1, const float* __restrict__ b1,
             const float* __restrict__ g, const float* __restrict__ be,
             const float* __restrict__ W2, const float* __restrict__ b2,
             float* __restrict__ tbl, int in_dim, int n_w1_rows)
{
    const int row = blockIdx.x;
    const int t = threadIdx.x;
    __shared__ float h[MIDK];
    __shared__ float red[512];
    float v = 0.f;
    if (t < in_dim) v = b1[t] + (row < n_w1_rows ? W1[row * in_dim + t] : 0.f);
    red[t] = (t < in_dim) ? v : 0.f;
    __syncthreads();
    for (int o = 256; o > 0; o >>= 1) { if (t < o) red[t] += red[t + o]; __syncthreads(); }
    float m = red[0] / (float)in_dim;
    __syncthreads();
    float d = v - m;
    red[t] = (t < in_dim) ? d * d : 0.f;
    __syncthreads();
    for (int o = 256; o > 0; o >>= 1) { if (t < o) red[t] += red[t + o]; __syncthreads(); }
    float rs = rsqrtf(red[0] / (float)in_dim + 1e-5f);
    __syncthreads();
    if (t < in_dim) h[t] = mishf(d * rs * g[t] + be[t]);
    __syncthreads();
    float acc = b2[t];
    for (int k = 0; k < in_dim; ++k) acc = fmaf(h[k], W2[k * HIDN + t], acc);
    tbl[row * HIDN + t] = acc;
}

// z init with cardinality term: z[b,c] = n_b * cardW[c] + cardb[c]
__global__ __launch_bounds__(256)
void k_card(const int* __restrict__ starts, const float* __restrict__ cardW,
            const float* __restrict__ cardb, float* __restrict__ z)
{
    int idx = blockIdx.x * 256 + threadIdx.x;   // < 2048*512
    int b = idx >> 9, c = idx & 511;
    float n = (float)(starts[b + 1] - starts[b]);
    z[idx] = fmaf(n, cardW[c], cardb[c]);
}

// In-place LayerNorm + mish over rows of Htmp [NPTS, 384]
__global__ __launch_bounds__(128)
void k_lnmish(float* __restrict__ H, const float* __restrict__ g,
              const float* __restrict__ be)
{
    const int row = blockIdx.x;
    float* p = H + (size_t)row * MIDV;
    const int t = threadIdx.x;
    float v0 = p[t], v1 = p[t + 128], v2 = p[t + 256];
    __shared__ float red[128];
    red[t] = v0 + v1 + v2;
    __syncthreads();
    for (int o = 64; o > 0; o >>= 1) { if (t < o) red[t] += red[t + o]; __syncthreads(); }
    float m = red[0] * (1.f / 384.f);
    __syncthreads();
    float d0 = v0 - m, d1 = v1 - m, d2 = v2 - m;
    red[t] = d0 * d0 + d1 * d1 + d2 * d2;
    __syncthreads();
    for (int o = 64; o > 0; o >>= 1) { if (t < o) red[t] += red[t + o]; __syncthreads(); }
    float rs = rsqrtf(red[0] * (1.f / 384.f) + 1e-5f);
    p[t]       = mishf(d0 * rs * g[t]       + be[t]);
    p[t + 128] = mishf(d1 * rs * g[t + 128] + be[t + 128]);
    p[t + 256] = mishf(d2 * rs * g[t + 256] + be[t + 256]);
}

// d_size MLP: one block per batch row of z -> n_dec[b]
__global__ __launch_bounds__(256)
void k_size(const float* __restrict__ z, const float* __restrict__ W1,
            const float* __restrict__ b1, const float* __restrict__ g,
            const float* __restrict__ be, const float* __restrict__ W2,
            const float* __restrict__ b2, int* __restrict__ ndec)
{
    const int b = blockIdx.x, t = threadIdx.x;
    __shared__ float zr[HIDN];
    __shared__ float red[256];
    zr[t] = z[b * HIDN + t];
    zr[t + 256] = z[b * HIDN + 256 + t];
    __syncthreads();
    float acc = b1[t];
    for (int k = 0; k < HIDN; ++k) acc = fmaf(zr[k], W1[k * MIDS + t], acc);
    red[t] = acc;
    __syncthreads();
    for (int o = 128; o > 0; o >>= 1) { if (t < o) red[t] += red[t + o]; __syncthreads(); }
    float m = red[0] * (1.f / 256.f);
    __syncthreads();
    float d = acc - m;
    red[t] = d * d;
    __syncthreads();
    for (int o = 128; o > 0; o >>= 1) { if (t < o) red[t] += red[t + o]; __syncthreads(); }
    float rs = rsqrtf(red[0] * (1.f / 256.f) + 1e-5f);
    __syncthreads();
    float h = mishf(d * rs * g[t] + be[t]);
    red[t] = h * W2[t];
    __syncthreads();
    for (int o = 128; o > 0; o >>= 1) { if (t < o) red[t] += red[t + o]; __syncthreads(); }
    if (t == 0) {
        float logit = red[0] + b2[0];
        float n = rintf(logit);
        n = fminf(fmaxf(n, 0.f), 64.f);
        ndec[b] = (int)n;
    }
}

// batch_out + mask outputs
__global__ __launch_bounds__(256)
void k_tail(const int* __restrict__ ndec, float* __restrict__ outb,
            float* __restrict__ outm)
{
    int r = blockIdx.x * 256 + threadIdx.x;
    if (r < NB * MAXNN) {
        outb[r] = (float)(r >> 6);
        outm[r] = ((r & 63) < ndec[r >> 6]) ? 1.f : 0.f;
    }
}

// ---------------- tiled GEMM, 4 fused modes ----------------
// MODE 0 (E1): C=Htmp f32 <- x @ e_val_W1 + b1
// MODE 1 (E2): y=(Htmp @ e_val_W2 + b2) * enc_tbl[kidx[row]]; grouped atomicAdd into z[batch[row]]
// MODE 2 (D1): A[r,k]=z[r>>6,k]*dec_tbl[r&63,k]; C=Hd bf16 <- mish(A @ d_dec_W1 + b1)
// MODE 3 (D2): C=out_x f32 <- (Hd @ d_dec_W2 + b2) masked by (r&63) < ndec[r>>6]
template<int MODE>
__global__ __launch_bounds__(256, 2)
void k_gemm(const void* __restrict__ Aptr, const float* __restrict__ Bptr,
            const float* __restrict__ bias, void* __restrict__ Cptr,
            int M, int K, int Nc,
            const float* __restrict__ tbl, const int* __restrict__ kidx,
            const int* __restrict__ batch, float* __restrict__ zout,
            const float* __restrict__ zin, const int* __restrict__ ndec)
{
    __shared__ float As[16][132];
    __shared__ float Bs[16][132];
    const int t = threadIdx.x;
    const int n0 = blockIdx.x * 128;
    const int m0 = blockIdx.y * 128;
    const int tm = t >> 4, tn = t & 15;
    const int rm0 = tm * 8, cn0 = tn * 8;
    float acc[8][8];
    #pragma unroll
    for (int r = 0; r < 8; ++r)
        #pragma unroll
        for (int c = 0; c < 8; ++c) acc[r][c] = 0.f;

    for (int k0 = 0; k0 < K; k0 += 16) {
        #pragma unroll
        for (int i = 0; i < 2; ++i) {
            int f = t * 2 + i;
            int m = f >> 2;
            int kq = (f & 3) << 2;
            float4 v;
            if (MODE == 0 || MODE == 1) {
                const float* A = (const float*)Aptr;
                v = *(const float4*)(A + (size_t)(m0 + m) * K + (k0 + kq));
            } else if (MODE == 2) {
                int gm = m0 + m;
                float4 zv = *(const float4*)(zin + ((gm >> 6) * HIDN + k0 + kq));
                float4 kv = *(const float4*)(tbl + ((gm & 63) * HIDN + k0 + kq));
                v = make_float4(zv.x * kv.x, zv.y * kv.y, zv.z * kv.z, zv.w * kv.w);
            } else {
                const unsigned short* A = (const unsigned short*)Aptr;
                ushort4 u = *(const ushort4*)(A + (size_t)(m0 + m) * K + (k0 + kq));
                v = make_float4(bf2f(u.x), bf2f(u.y), bf2f(u.z), bf2f(u.w));
            }
            As[kq + 0][m] = v.x; As[kq + 1][m] = v.y;
            As[kq + 2][m] = v.z; As[kq + 3][m] = v.w;
        }
        #pragma unroll
        for (int i = 0; i < 2; ++i) {
            int f = t + i * 256;
            int kk = f >> 5;
            int nn = (f & 31) << 2;
            float4 v = *(const float4*)(Bptr + (size_t)(k0 + kk) * Nc + (n0 + nn));
            *(float4*)&Bs[kk][nn] = v;
        }
        __syncthreads();
        #pragma unroll
        for (int k = 0; k < 16; ++k) {
            float4 a0 = *(const float4*)&As[k][rm0];
            float4 a1 = *(const float4*)&As[k][rm0 + 4];
            float4 b0 = *(const float4*)&Bs[k][cn0];
            float4 b1v = *(const float4*)&Bs[k][cn0 + 4];
            float av[8] = {a0.x, a0.y, a0.z, a0.w, a1.x, a1.y, a1.z, a1.w};
            float bv[8] = {b0.x, b0.y, b0.z, b0.w, b1v.x, b1v.y, b1v.z, b1v.w};
            #pragma unroll
            for (int r = 0; r < 8; ++r)
                #pragma unroll
                for (int c = 0; c < 8; ++c)
                    acc[r][c] = fmaf(av[r], bv[c], acc[r][c]);
        }
        __syncthreads();
    }

    const int col0 = n0 + cn0;
    float bb[8];
    #pragma unroll
    for (int c = 0; c < 8; ++c) bb[c] = bias[col0 + c];

    if (MODE == 0) {
        float* C = (float*)Cptr;
        #pragma unroll
        for (int r = 0; r < 8; ++r) {
            int gm = m0 + rm0 + r;
            float4 v0 = make_float4(acc[r][0] + bb[0], acc[r][1] + bb[1],
                                    acc[r][2] + bb[2], acc[r][3] + bb[3]);
            float4 v1 = make_float4(acc[r][4] + bb[4], acc[r][5] + bb[5],
                                    acc[r][6] + bb[6], acc[r][7] + bb[7]);
            *(float4*)(C + (size_t)gm * Nc + col0) = v0;
            *(float4*)(C + (size_t)gm * Nc + col0 + 4) = v1;
        }
    } else if (MODE == 1) {
        float run[8];
        int curb = -1;
        #pragma unroll
        for (int r = 0; r < 8; ++r) {
            int gm = m0 + rm0 + r;
            int b = batch[gm];
            int ki = kidx[gm];
            const float* trow = tbl + ki * HIDN + col0;
            float vals[8];
            #pragma unroll
            for (int c = 0; c < 8; ++c) vals[c] = (acc[r][c] + bb[c]) * trow[c];
            if (b != curb) {
                if (curb >= 0) {
                    #pragma unroll
                    for (int c = 0; c < 8; ++c) atomicAdd(&zout[curb * HIDN + col0 + c], run[c]);
                }
                curb = b;
                #pragma unroll
                for (int c = 0; c < 8; ++c) run[c] = vals[c];
            } else {
                #pragma unroll
                for (int c = 0; c < 8; ++c) run[c] += vals[c];
            }
        }
        #pragma unroll
        for (int c = 0; c < 8; ++c) atomicAdd(&zout[curb * HIDN + col0 + c], run[c]);
    } else if (MODE == 2) {
        unsigned short* C = (unsigned short*)Cptr;
        #pragma unroll
        for (int r = 0; r < 8; ++r) {
            int gm = m0 + rm0 + r;
            ushort4 u0, u1;
            u0.x = f2bf(mishf(acc[r][0] + bb[0])); u0.y = f2bf(mishf(acc[r][1] + bb[1]));
            u0.z = f2bf(mishf(acc[r][2] + bb[2])); u0.w = f2bf(mishf(acc[r][3] + bb[3]));
            u1.x = f2bf(mishf(acc[r][4] + bb[4])); u1.y = f2bf(mishf(acc[r][5] + bb[5]));
            u1.z = f2bf(mishf(acc[r][6] + bb[6])); u1.w = f2bf(mishf(acc[r][7] + bb[7]));
            *(ushort4*)(C + (size_t)gm * Nc + col0) = u0;
            *(ushort4*)(C + (size_t)gm * Nc + col0 + 4) = u1;
        }
    } else {
        float* C = (float*)Cptr;
        #pragma unroll
        for (int r = 0; r < 8; ++r) {
            int gm = m0 + rm0 + r;
            bool keep = (gm & 63) < ndec[gm >> 6];
            float4 v0, v1;
            if (keep) {
                v0 = make_float4(acc[r][0] + bb[0], acc[r][1] + bb[1],
                                 acc[r][2] + bb[2], acc[r][3] + bb[3]);
                v1 = make_float4(acc[r][4] + bb[4], acc[r][5] + bb[5],
                                 acc[r][6] + bb[6], acc[r][7] + bb[7]);
            } else {
                v0 = make_float4(0.f, 0.f, 0.f, 0.f);
                v1 = v0;
            }
            *(float4*)(C + (size_t)gm * Nc + col0) = v0;
            *(float4*)(C + (size_t)gm * Nc + col0 + 4) = v1;
        }
    }
}

// ---------------- launch ----------------
extern "C" void kernel_launch(void* const* d_in, const int* in_sizes, int n_in,
                              void* d_out, int out_size, void* d_ws, size_t ws_size,
                              hipStream_t stream)
{
    const float* x        = (const float*)d_in[0];
    const int*   batch    = (const int*)  d_in[1];
    const float* e_rank_W = (const float*)d_in[3];
    const float* e_rank_b = (const float*)d_in[4];
    const float* e_card_W = (const float*)d_in[5];
    const float* e_card_b = (const float*)d_in[6];
    const float* e_key_W1 = (const float*)d_in[7];
    const float* e_key_b1 = (const float*)d_in[8];
    const float* e_key_g  = (const float*)d_in[9];
    const float* e_key_be = (const float*)d_in[10];
    const float* e_key_W2 = (const float*)d_in[11];
    const float* e_key_b2 = (const float*)d_in[12];
    const float* e_val_W1 = (const float*)d_in[13];
    const float* e_val_b1 = (const float*)d_in[14];
    const float* e_val_g  = (const float*)d_in[15];
    const float* e_val_be = (const float*)d_in[16];
    const float* e_val_W2 = (const float*)d_in[17];
    const float* e_val_b2 = (const float*)d_in[18];
    const float* d_key_W1 = (const float*)d_in[19];
    const float* d_key_b1 = (const float*)d_in[20];
    const float* d_key_g  = (const float*)d_in[21];
    const float* d_key_be = (const float*)d_in[22];
    const float* d_key_W2 = (const float*)d_in[23];
    const float* d_key_b2 = (const float*)d_in[24];
    const float* d_dec_W1 = (const float*)d_in[25];
    const float* d_dec_b1 = (const float*)d_in[26];
    const float* d_dec_W2 = (const float*)d_in[27];
    const float* d_dec_b2 = (const float*)d_in[28];
    const float* d_size_W1= (const float*)d_in[29];
    const float* d_size_b1= (const float*)d_in[30];
    const float* d_size_g = (const float*)d_in[31];
    const float* d_size_be= (const float*)d_in[32];
    const float* d_size_W2= (const float*)d_in[33];
    const float* d_size_b2= (const float*)d_in[34];

    char* ws = (char*)d_ws;
    int*           starts  = (int*)          (ws + 0);         //  8196 B
    unsigned int*  maxmag  = (unsigned int*) (ws + 8448);      //  4 B
    int*           kidx    = (int*)          (ws + 8704);      //  262144 B
    float*         mag     = (float*)        (ws + 270848);    //  262144 B
    float*         enc_tbl = (float*)        (ws + 532992);    //  65*512*4
    float*         dec_tbl = (float*)        (ws + 666112);    //  64*512*4
    float*         z       = (float*)        (ws + 797184);    //  2048*512*4
    int*           ndec    = (int*)          (ws + 4991488);   //  2048*4
    float*         Htmp    = (float*)        (ws + 4999680);   //  65536*384*4
    unsigned short* Hd     = (unsigned short*)(ws + 4999680);  //  131072*384*2 (same size, reused)

    float* out_x = (float*)d_out;                  // [131072, 256]
    float* out_b = out_x + (size_t)NB * MAXNN * DIMX;
    float* out_m = out_b + NB * MAXNN;

    k_starts<<<dim3(9), dim3(256), 0, stream>>>(batch, starts, maxmag);
    k_mag<<<dim3(1024), dim3(256), 0, stream>>>(x, e_rank_W, e_rank_b, mag, maxmag);
    k_rank<<<dim3(256), dim3(256), 0, stream>>>(batch, starts, mag, maxmag, kidx);
    k_table<<<dim3(65), dim3(512), 0, stream>>>(e_key_W1, e_key_b1, e_key_g, e_key_be,
                                                e_key_W2, e_key_b2, enc_tbl, MIDK, 64);
    k_table<<<dim3(64), dim3(512), 0, stream>>>(d_key_W1, d_key_b1, d_key_g, d_key_be,
                                                d_key_W2, d_key_b2, dec_tbl, MIDK, 64);
    k_card<<<dim3(4096), dim3(256), 0, stream>>>(starts, e_card_W, e_card_b, z);

    // E1: Htmp = x @ e_val_W1 + b1
    k_gemm<0><<<dim3(3, 512), dim3(256), 0, stream>>>(
        x, e_val_W1, e_val_b1, Htmp, NPTS, DIMX, MIDV,
        (const float*)nullptr, (const int*)nullptr, (const int*)nullptr,
        (float*)nullptr, (const float*)nullptr, (const int*)nullptr);
    // LN + mish in place
    k_lnmish<<<dim3(NPTS), dim3(128), 0, stream>>>(Htmp, e_val_g, e_val_be);
    // E2: z += segment-sum over rows of (Htmp @ e_val_W2 + b2) * enc_tbl[kidx]
    k_gemm<1><<<dim3(4, 512), dim3(256), 0, stream>>>(
        Htmp, e_val_W2, e_val_b2, (void*)nullptr, NPTS, MIDV, HIDN,
        enc_tbl, kidx, batch, z, (const float*)nullptr, (const int*)nullptr);
    // size head -> n_dec
    k_size<<<dim3(NB), dim3(256), 0, stream>>>(z, d_size_W1, d_size_b1, d_size_g,
                                               d_size_be, d_size_W2, d_size_b2, ndec);
    // D1: Hd = bf16(mish((z*keys) @ d_dec_W1 + b1))
    k_gemm<2><<<dim3(3, 1024), dim3(256), 0, stream>>>(
        (const void*)nullptr, d_dec_W1, d_dec_b1, Hd, NB * MAXNN, HIDN, MIDD,
        dec_tbl, (const int*)nullptr, (const int*)nullptr,
        (float*)nullptr, z, (const int*)nullptr);
    // D2: out_x = masked(Hd @ d_dec_W2 + b2)
    k_gemm<3><<<dim3(2, 1024), dim3(256), 0, stream>>>(
        Hd, d_dec_W2, d_dec_b2, out_x, NB * MAXNN, MIDD, DIMX,
        (const float*)nullptr, (const int*)nullptr, (const int*)nullptr,
        (float*)nullptr, (const float*)nullptr, ndec);
    // batch_out + mask
    k_tail<<<dim3(512), dim3(256), 0, stream>>>(ndec, out_b, out_m);
}

// Round 2
// 681.651 us; speedup vs baseline: 2.8433x; 2.8433x over previous
//
#include <hip/hip_runtime.h>

#define NPTS   65536
#define NB     2048
#define DIMX   256
#define HIDN   512
#define MAXNN  64
#define MIDK   288
#define MIDV   384
#define MIDD   384
#define MIDS   256

typedef unsigned short ushort_t;
typedef __attribute__((ext_vector_type(8))) short short8;
typedef __attribute__((ext_vector_type(4))) float f32x4;

// ---------------- helpers ----------------
__device__ __forceinline__ float mishf(float x) {
    float sp = (x > 20.f) ? x : log1pf(expf(x));
    return x * tanhf(sp);
}
__device__ __forceinline__ ushort_t f2bf(float f) {
    unsigned u = __float_as_uint(f);
    u += 0x7fffu + ((u >> 16) & 1u);
    return (ushort_t)(u >> 16);
}
__device__ __forceinline__ float bf2f(ushort_t h) {
    return __uint_as_float(((unsigned)h) << 16);
}
// async global->LDS DMA, 16B per lane. LDS dest = wave-uniform base + lane*16.
__device__ __forceinline__ void dma16(const void* g, void* lds) {
    __builtin_amdgcn_global_load_lds(
        (const __attribute__((address_space(1))) unsigned int*)g,
        (__attribute__((address_space(3))) unsigned int*)lds, 16, 0, 0);
}

// ---------------- small kernels ----------------
__global__ __launch_bounds__(256)
void k_starts(const int* __restrict__ batch, int* __restrict__ starts,
              unsigned int* __restrict__ maxmag, int* __restrict__ cnt)
{
    int b = blockIdx.x * blockDim.x + threadIdx.x;
    if (b == 0) { *maxmag = 0u; *cnt = 0; }
    if (b <= NB) {
        int lo = 0, hi = NPTS;
        while (lo < hi) { int mid = (lo + hi) >> 1; if (batch[mid] < b) lo = mid + 1; else hi = mid; }
        starts[b] = lo;
    }
}

// mag[i] = |x[i,:]@rW + rb| (f64 accumulate) + global max; also x -> bf16.
__global__ __launch_bounds__(256)
void k_mag(const float* __restrict__ x, const float* __restrict__ rW,
           const float* __restrict__ rb, float* __restrict__ mag,
           unsigned int* __restrict__ maxmag, ushort_t* __restrict__ xb)
{
    const int lane = threadIdx.x & 63;
    const int wave = threadIdx.x >> 6;
    const int gw = blockIdx.x * 4 + wave;   // 4096 waves total
    float4 wv = *(const float4*)(rW + lane * 4);
    float bias = rb[0];
    float lmax = 0.f;
    for (int pt = gw; pt < NPTS; pt += 4096) {
        float4 xv = *(const float4*)(x + (size_t)pt * DIMX + lane * 4);
        ushort4 u;
        u.x = f2bf(xv.x); u.y = f2bf(xv.y); u.z = f2bf(xv.z); u.w = f2bf(xv.w);
        *(ushort4*)(xb + (size_t)pt * DIMX + lane * 4) = u;
        double d = (double)xv.x * wv.x + (double)xv.y * wv.y
                 + (double)xv.z * wv.z + (double)xv.w * wv.w;
        #pragma unroll
        for (int o = 32; o > 0; o >>= 1) d += __shfl_xor(d, o);
        float s = fabsf((float)(d + (double)bias));
        if (lane == 0) mag[pt] = s;
        lmax = fmaxf(lmax, s);
    }
    __shared__ float wm[4];
    if (lane == 0) wm[wave] = lmax;
    __syncthreads();
    if (threadIdx.x == 0) {
        float m = fmaxf(fmaxf(wm[0], wm[1]), fmaxf(wm[2], wm[3]));
        atomicMax(maxmag, __float_as_uint(m));
    }
}

__global__ __launch_bounds__(256)
void k_rank(const int* __restrict__ batch, const int* __restrict__ starts,
            const float* __restrict__ mag, const unsigned int* __restrict__ maxmag,
            int* __restrict__ kidx)
{
    int i = blockIdx.x * 256 + threadIdx.x;
    if (i >= NPTS) return;
    int b = batch[i];
    int s = starts[b], e = starts[b + 1];
    float M = __uint_as_float(*maxmag);
    float kb = __fmul_rn((float)b, M);
    float ki = __fadd_rn(kb, mag[i]);
    int r = 0;
    for (int j = s; j < e; ++j) {
        float kj = __fadd_rn(kb, mag[j]);
        r += (kj < ki) || (kj == ki && j < i);
    }
    kidx[i] = (r < MAXNN) ? r : MAXNN;
}

__global__ __launch_bounds__(512)
void k_table(const float* __restrict__ W1, const float* __restrict__ b1,
             const float* __restrict__ g, const float* __restrict__ be,
             const float* __restrict__ W2, const float* __restrict__ b2,
             float* __restrict__ tbl, int in_dim, int n_w1_rows)
{
    const int row = blockIdx.x;
    const int t = threadIdx.x;
    __shared__ float h[MIDK];
    __shared__ float red[512];
    float v = 0.f;
    if (t < in_dim) v = b1[t] + (row < n_w1_rows ? W1[row * in_dim + t] : 0.f);
    red[t] = (t < in_dim) ? v : 0.f;
    __syncthreads();
    for (int o = 256; o > 0; o >>= 1) { if (t < o) red[t] += red[t + o]; __syncthreads(); }
    float m = red[0] / (float)in_dim;
    __syncthreads();
    float d = v - m;
    red[t] = (t < in_dim) ? d * d : 0.f;
    __syncthreads();
    for (int o = 256; o > 0; o >>= 1) { if (t < o) red[t] += red[t + o]; __syncthreads(); }
    float rs = rsqrtf(red[0] / (float)in_dim + 1e-5f);
    __syncthreads();
    if (t < in_dim) h[t] = mishf(d * rs * g[t] + be[t]);
    __syncthreads();
    float acc = b2[t];
    for (int k = 0; k < in_dim; ++k) acc = fmaf(h[k], W2[k * HIDN + t], acc);
    tbl[row * HIDN + t] = acc;
}

__global__ __launch_bounds__(256)
void k_card(const int* __restrict__ starts, const float* __restrict__ cardW,
            const float* __restrict__ cardb, float* __restrict__ z)
{
    int idx = blockIdx.x * 256 + threadIdx.x;
    int b = idx >> 9, c = idx & 511;
    float n = (float)(starts[b + 1] - starts[b]);
    z[idx] = fmaf(n, cardW[c], cardb[c]);
}

// In-place LayerNorm + mish over bf16 rows [NPTS, 384]
__global__ __launch_bounds__(128)
void k_lnmish(ushort_t* __restrict__ H, const float* __restrict__ g,
              const float* __restrict__ be)
{
    const int row = blockIdx.x;
    ushort_t* p = H + (size_t)row * MIDV;
    const int t = threadIdx.x;
    float v0 = bf2f(p[t]), v1 = bf2f(p[t + 128]), v2 = bf2f(p[t + 256]);
    __shared__ float red[128];
    red[t] = v0 + v1 + v2;
    __syncthreads();
    for (int o = 64; o > 0; o >>= 1) { if (t < o) red[t] += red[t + o]; __syncthreads(); }
    float m = red[0] * (1.f / 384.f);
    __syncthreads();
    float d0 = v0 - m, d1 = v1 - m, d2 = v2 - m;
    red[t] = d0 * d0 + d1 * d1 + d2 * d2;
    __syncthreads();
    for (int o = 64; o > 0; o >>= 1) { if (t < o) red[t] += red[t + o]; __syncthreads(); }
    float rs = rsqrtf(red[0] * (1.f / 384.f) + 1e-5f);
    p[t]       = f2bf(mishf(d0 * rs * g[t]       + be[t]));
    p[t + 128] = f2bf(mishf(d1 * rs * g[t + 128] + be[t + 128]));
    p[t + 256] = f2bf(mishf(d2 * rs * g[t + 256] + be[t + 256]));
}

__global__ __launch_bounds__(256)
void k_size(const float* __restrict__ z, const float* __restrict__ W1,
            const float* __restrict__ b1, const float* __restrict__ g,
            const float* __restrict__ be, const float* __restrict__ W2,
            const float* __restrict__ b2, int* __restrict__ ndec)
{
    const int b = blockIdx.x, t = threadIdx.x;
    __shared__ float zr[HIDN];
    __shared__ float red[256];
    zr[t] = z[b * HIDN + t];
    zr[t + 256] = z[b * HIDN + 256 + t];
    __syncthreads();
    float acc = b1[t];
    for (int k = 0; k < HIDN; ++k) acc = fmaf(zr[k], W1[k * MIDS + t], acc);
    red[t] = acc;
    __syncthreads();
    for (int o = 128; o > 0; o >>= 1) { if (t < o) red[t] += red[t + o]; __syncthreads(); }
    float m = red[0] * (1.f / 256.f);
    __syncthreads();
    float d = acc - m;
    red[t] = d * d;
    __syncthreads();
    for (int o = 128; o > 0; o >>= 1) { if (t < o) red[t] += red[t + o]; __syncthreads(); }
    float rs = rsqrtf(red[0] * (1.f / 256.f) + 1e-5f);
    __syncthreads();
    float h = mishf(d * rs * g[t] + be[t]);
    red[t] = h * W2[t];
    __syncthreads();
    for (int o = 128; o > 0; o >>= 1) { if (t < o) red[t] += red[t + o]; __syncthreads(); }
    if (t == 0) {
        float logit = red[0] + b2[0];
        float n = rintf(logit);
        n = fminf(fmaxf(n, 0.f), 64.f);
        ndec[b] = (int)n;
    }
}

// active-row compaction (order within rowmap is arbitrary; outputs are disjoint)
__global__ __launch_bounds__(256)
void k_compact(const int* __restrict__ ndec, int* __restrict__ cnt,
               int* __restrict__ rowmap)
{
    int b = blockIdx.x * 256 + threadIdx.x;
    if (b >= NB) return;
    int n = ndec[b];
    if (n > 0) {
        int base = atomicAdd(cnt, n);
        for (int p = 0; p < n; ++p) rowmap[base + p] = b * 64 + p;
    }
}

__global__ __launch_bounds__(128)
void k_pad(const int* __restrict__ cnt, int* __restrict__ cntpad,
           int* __restrict__ rowmap)
{
    int c = *cnt;
    int pad = (c + 127) & ~127;
    int t = threadIdx.x;
    if (c + t < pad) rowmap[c + t] = -1;
    if (t == 0) *cntpad = pad;
}

__global__ __launch_bounds__(256)
void k_tail(const int* __restrict__ ndec, float* __restrict__ outb,
            float* __restrict__ outm)
{
    int r = blockIdx.x * 256 + threadIdx.x;
    if (r < NB * MAXNN) {
        outb[r] = (float)(r >> 6);
        outm[r] = ((r & 63) < ndec[r >> 6]) ? 1.f : 0.f;
    }
}

// W [K][N] f32 -> Wt [N][K] bf16
__global__ __launch_bounds__(256)
void k_wt(const float* __restrict__ W, ushort_t* __restrict__ Wt, int K, int N)
{
    int idx = blockIdx.x * 256 + threadIdx.x;
    if (idx >= K * N) return;
    int k = idx / N, n = idx - k * N;
    Wt[(size_t)n * K + k] = f2bf(W[idx]);
}

// ---------------- MFMA GEMM, 4 fused modes ----------------
// 128x128 tile, BK=64, 4 waves each computing 64x64 via 4x4 16x16x32 frags.
// A [M][K] bf16 row-major, Bt [N][K] bf16. XOR swizzle: phys kblk = logical ^ (row&7).
// MODE 0 (E1): C=Hb bf16 <- xb @ W1t + b1            (stride MIDV)
// MODE 1 (E2): (Hb @ W2t + b2) * enc_tbl[kidx]; segment atomicAdd into z[batch]
// MODE 2 (D1): A=z[rm>>6]*dec_tbl[rm&63] on the fly; C=Hd bf16 <- mish(.)  (stride MIDD)
// MODE 3 (D2): scatter out_x[rowmap[r]] <- Hd @ W2t + b2                   (stride DIMX)
template<int MODE>
__global__ __launch_bounds__(256, 2)
void k_mm(const ushort_t* __restrict__ A, const ushort_t* __restrict__ Bt,
          const float* __restrict__ bias, void* __restrict__ Cptr, int K,
          const float* __restrict__ tbl, const int* __restrict__ kidx,
          const int* __restrict__ batch, float* __restrict__ zout,
          const float* __restrict__ zin, const int* __restrict__ rowmap,
          const int* __restrict__ cntpad)
{
    const int n0 = blockIdx.x * 128;
    const int m0 = blockIdx.y * 128;
    if (MODE >= 2) {
        if (m0 >= *cntpad) return;
    }
    __shared__ __align__(16) ushort_t As[128 * 64];
    __shared__ __align__(16) ushort_t Bs[128 * 64];
    const int t = threadIdx.x;
    const int l = t & 63;
    const int w = t >> 6;
    const int wm = (w >> 1) * 64;
    const int wn = (w & 1) * 64;
    const int drow = l >> 3;             // 0..7 within 8-row DMA group
    const int dblk = (l & 7) ^ drow;     // logical k-block this lane fetches

    int g4[4], p4[4];
    if (MODE == 2) {
        #pragma unroll
        for (int ii = 0; ii < 4; ++ii) {
            int i = w * 4 + ii;
            int gr = rowmap[m0 + i * 8 + drow];
            if (gr < 0) gr = 0;
            g4[ii] = gr >> 6; p4[ii] = gr & 63;
        }
    }

    f32x4 acc[4][4];
    #pragma unroll
    for (int a = 0; a < 4; ++a)
        #pragma unroll
        for (int b = 0; b < 4; ++b) acc[a][b] = (f32x4)0.f;

    for (int k0 = 0; k0 < K; k0 += 64) {
        if (MODE == 2) {
            #pragma unroll
            for (int ii = 0; ii < 4; ++ii) {
                int i = w * 4 + ii;
                int row = i * 8 + drow;
                const float* zp = zin + g4[ii] * HIDN + k0 + dblk * 8;
                const float* kp = tbl + p4[ii] * HIDN + k0 + dblk * 8;
                float4 z0 = *(const float4*)zp;
                float4 z1 = *(const float4*)(zp + 4);
                float4 q0 = *(const float4*)kp;
                float4 q1 = *(const float4*)(kp + 4);
                ushort4 u0, u1;
                u0.x = f2bf(z0.x * q0.x); u0.y = f2bf(z0.y * q0.y);
                u0.z = f2bf(z0.z * q0.z); u0.w = f2bf(z0.w * q0.w);
                u1.x = f2bf(z1.x * q1.x); u1.y = f2bf(z1.y * q1.y);
                u1.z = f2bf(z1.z * q1.z); u1.w = f2bf(z1.w * q1.w);
                ushort_t* dst = &As[row * 64 + (l & 7) * 8];   // phys blk = logical^ (row&7)
                *(ushort4*)dst = u0;
                *(ushort4*)(dst + 4) = u1;
            }
        } else {
            #pragma unroll
            for (int ii = 0; ii < 4; ++ii) {
                int i = w * 4 + ii;
                const ushort_t* g = A + (size_t)(m0 + i * 8 + drow) * K + k0 + dblk * 8;
                dma16(g, &As[i * 512]);
            }
        }
        #pragma unroll
        for (int ii = 0; ii < 4; ++ii) {
            int i = w * 4 + ii;
            const ushort_t* g = Bt + (size_t)(n0 + i * 8 + drow) * K + k0 + dblk * 8;
            dma16(g, &Bs[i * 512]);
        }
        __syncthreads();
        #pragma unroll
        for (int ks = 0; ks < 2; ++ks) {
            short8 af[4], bfr[4];
            int kq = ks * 4 + (l >> 4);
            #pragma unroll
            for (int fm = 0; fm < 4; ++fm) {
                int row = wm + fm * 16 + (l & 15);
                af[fm] = *(const short8*)&As[row * 64 + ((kq ^ (row & 7)) << 3)];
            }
            #pragma unroll
            for (int fn = 0; fn < 4; ++fn) {
                int row = wn + fn * 16 + (l & 15);
                bfr[fn] = *(const short8*)&Bs[row * 64 + ((kq ^ (row & 7)) << 3)];
            }
            #pragma unroll
            for (int fm = 0; fm < 4; ++fm)
                #pragma unroll
                for (int fn = 0; fn < 4; ++fn)
                    acc[fm][fn] = __builtin_amdgcn_mfma_f32_16x16x32_bf16(
                        af[fm], bfr[fn], acc[fm][fn], 0, 0, 0);
        }
        __syncthreads();
    }

    const int l4 = (l >> 4) << 2;
    if (MODE == 0) {
        ushort_t* C = (ushort_t*)Cptr;
        #pragma unroll
        for (int fm = 0; fm < 4; ++fm) {
            int gr0 = m0 + wm + fm * 16 + l4;
            #pragma unroll
            for (int fn = 0; fn < 4; ++fn) {
                int gc = n0 + wn + fn * 16 + (l & 15);
                float bb = bias[gc];
                #pragma unroll
                for (int j = 0; j < 4; ++j)
                    C[(size_t)(gr0 + j) * MIDV + gc] = f2bf(acc[fm][fn][j] + bb);
            }
        }
    } else if (MODE == 1) {
        #pragma unroll
        for (int fm = 0; fm < 4; ++fm) {
            int gr0 = m0 + wm + fm * 16 + l4;
            int bt[4], ki[4];
            #pragma unroll
            for (int j = 0; j < 4; ++j) { bt[j] = batch[gr0 + j]; ki[j] = kidx[gr0 + j]; }
            #pragma unroll
            for (int fn = 0; fn < 4; ++fn) {
                int gc = n0 + wn + fn * 16 + (l & 15);
                float bb = bias[gc];
                float run = 0.f; int curb = bt[0];
                #pragma unroll
                for (int j = 0; j < 4; ++j) {
                    float v = (acc[fm][fn][j] + bb) * tbl[ki[j] * HIDN + gc];
                    if (bt[j] != curb) {
                        atomicAdd(&zout[curb * HIDN + gc], run);
                        curb = bt[j]; run = v;
                    } else run += v;
                }
                atomicAdd(&zout[curb * HIDN + gc], run);
            }
        }
    } else if (MODE == 2) {
        ushort_t* C = (ushort_t*)Cptr;
        #pragma unroll
        for (int fm = 0; fm < 4; ++fm) {
            int gr0 = m0 + wm + fm * 16 + l4;
            #pragma unroll
            for (int fn = 0; fn < 4; ++fn) {
                int gc = n0 + wn + fn * 16 + (l & 15);
                float bb = bias[gc];
                #pragma unroll
                for (int j = 0; j < 4; ++j)
                    C[(size_t)(gr0 + j) * MIDD + gc] = f2bf(mishf(acc[fm][fn][j] + bb));
            }
        }
    } else {
        float* C = (float*)Cptr;
        #pragma unroll
        for (int fm = 0; fm < 4; ++fm) {
            int gr0 = m0 + wm + fm * 16 + l4;
            int om[4];
            #pragma unroll
            for (int j = 0; j < 4; ++j) om[j] = rowmap[gr0 + j];
            #pragma unroll
            for (int fn = 0; fn < 4; ++fn) {
                int gc = n0 + wn + fn * 16 + (l & 15);
                float bb = bias[gc];
                #pragma unroll
                for (int j = 0; j < 4; ++j)
                    if (om[j] >= 0) C[(size_t)om[j] * DIMX + gc] = acc[fm][fn][j] + bb;
            }
        }
    }
}

// ---------------- launch ----------------
extern "C" void kernel_launch(void* const* d_in, const int* in_sizes, int n_in,
                              void* d_out, int out_size, void* d_ws, size_t ws_size,
                              hipStream_t stream)
{
    const float* x        = (const float*)d_in[0];
    const int*   batch    = (const int*)  d_in[1];
    const float* e_rank_W = (const float*)d_in[3];
    const float* e_rank_b = (const float*)d_in[4];
    const float* e_card_W = (const float*)d_in[5];
    const float* e_card_b = (const float*)d_in[6];
    const float* e_key_W1 = (const float*)d_in[7];
    const float* e_key_b1 = (const float*)d_in[8];
    const float* e_key_g  = (const float*)d_in[9];
    const float* e_key_be = (const float*)d_in[10];
    const float* e_key_W2 = (const float*)d_in[11];
    const float* e_key_b2 = (const float*)d_in[12];
    const float* e_val_W1 = (const float*)d_in[13];
    const float* e_val_b1 = (const float*)d_in[14];
    const float* e_val_g  = (const float*)d_in[15];
    const float* e_val_be = (const float*)d_in[16];
    const float* e_val_W2 = (const float*)d_in[17];
    const float* e_val_b2 = (const float*)d_in[18];
    const float* d_key_W1 = (const float*)d_in[19];
    const float* d_key_b1 = (const float*)d_in[20];
    const float* d_key_g  = (const float*)d_in[21];
    const float* d_key_be = (const float*)d_in[22];
    const float* d_key_W2 = (const float*)d_in[23];
    const float* d_key_b2 = (const float*)d_in[24];
    const float* d_dec_W1 = (const float*)d_in[25];
    const float* d_dec_b1 = (const float*)d_in[26];
    const float* d_dec_W2 = (const float*)d_in[27];
    const float* d_dec_b2 = (const float*)d_in[28];
    const float* d_size_W1= (const float*)d_in[29];
    const float* d_size_b1= (const float*)d_in[30];
    const float* d_size_g = (const float*)d_in[31];
    const float* d_size_be= (const float*)d_in[32];
    const float* d_size_W2= (const float*)d_in[33];
    const float* d_size_b2= (const float*)d_in[34];

    char* ws = (char*)d_ws;
    int*          starts  = (int*)         (ws + 0);
    unsigned int* maxmag  = (unsigned int*)(ws + 8448);
    int*          kidx    = (int*)         (ws + 8704);
    float*        mag     = (float*)       (ws + 270848);
    float*        enc_tbl = (float*)       (ws + 532992);    // 65*512*4
    float*        dec_tbl = (float*)       (ws + 666112);    // 64*512*4
    float*        z       = (float*)       (ws + 797184);    // 2048*512*4
    int*          ndec    = (int*)         (ws + 4991488);   // 2048*4
    int*          cnt     = (int*)         (ws + 4999680);
    int*          cntpad  = (int*)         (ws + 4999684);
    int*          rowmap  = (int*)         (ws + 5000192);   // 131072*4
    ushort_t*     evW1t   = (ushort_t*)    (ws + 5524480);   // [384][256]
    ushort_t*     evW2t   = (ushort_t*)    (ws + 5721088);   // [512][384]
    ushort_t*     ddW1t   = (ushort_t*)    (ws + 6114304);   // [384][512]
    ushort_t*     ddW2t   = (ushort_t*)    (ws + 6507520);   // [256][384]
    // big region R (96 MB): xb+Hb live pre-decoder; Hd reuses it afterwards
    ushort_t*     xb      = (ushort_t*)    (ws + 6704384);               // 65536*256*2 = 32MB
    ushort_t*     Hb      = (ushort_t*)    (ws + 6704384 + 33554432);    // 65536*384*2 = 48MB
    ushort_t*     Hd      = (ushort_t*)    (ws + 6704384);               // 131072*384*2 = 96MB

    float* out_x = (float*)d_out;                  // [131072, 256]
    float* out_b = out_x + (size_t)NB * MAXNN * DIMX;
    float* out_m = out_b + NB * MAXNN;

    const ushort_t* NUS = nullptr; const float* NF = nullptr;
    const int* NI = nullptr;

    k_starts<<<dim3(9), dim3(256), 0, stream>>>(batch, starts, maxmag, cnt);
    k_mag<<<dim3(1024), dim3(256), 0, stream>>>(x, e_rank_W, e_rank_b, mag, maxmag, xb);
    k_rank<<<dim3(256), dim3(256), 0, stream>>>(batch, starts, mag, maxmag, kidx);
    k_table<<<dim3(65), dim3(512), 0, stream>>>(e_key_W1, e_key_b1, e_key_g, e_key_be,
                                                e_key_W2, e_key_b2, enc_tbl, MIDK, 64);
    k_table<<<dim3(64), dim3(512), 0, stream>>>(d_key_W1, d_key_b1, d_key_g, d_key_be,
                                                d_key_W2, d_key_b2, dec_tbl, MIDK, 64);
    k_card<<<dim3(4096), dim3(256), 0, stream>>>(starts, e_card_W, e_card_b, z);
    k_wt<<<dim3(384), dim3(256), 0, stream>>>(e_val_W1, evW1t, DIMX, MIDV);
    k_wt<<<dim3(768), dim3(256), 0, stream>>>(e_val_W2, evW2t, MIDV, HIDN);
    k_wt<<<dim3(768), dim3(256), 0, stream>>>(d_dec_W1, ddW1t, HIDN, MIDD);
    k_wt<<<dim3(384), dim3(256), 0, stream>>>(d_dec_W2, ddW2t, MIDD, DIMX);

    // E1: Hb = bf16(xb @ W1t + b1)
    k_mm<0><<<dim3(3, 512), dim3(256), 0, stream>>>(
        xb, evW1t, e_val_b1, Hb, DIMX, NF, NI, NI, (float*)nullptr, NF, NI, NI);
    k_lnmish<<<dim3(NPTS), dim3(128), 0, stream>>>(Hb, e_val_g, e_val_be);
    // E2: z += segsum((Hb @ W2t + b2) * enc_tbl[kidx])
    k_mm<1><<<dim3(4, 512), dim3(256), 0, stream>>>(
        Hb, evW2t, e_val_b2, nullptr, MIDV, enc_tbl, kidx, batch, z, NF, NI, NI);
    k_size<<<dim3(NB), dim3(256), 0, stream>>>(z, d_size_W1, d_size_b1, d_size_g,
                                               d_size_be, d_size_W2, d_size_b2, ndec);
    k_compact<<<dim3(8), dim3(256), 0, stream>>>(ndec, cnt, rowmap);
    k_pad<<<dim3(1), dim3(128), 0, stream>>>(cnt, cntpad, rowmap);
    hipMemsetAsync(out_x, 0, (size_t)NB * MAXNN * DIMX * sizeof(float), stream);
    // D1 (compacted): Hd = bf16(mish((z*keys) @ W1t + b1))
    k_mm<2><<<dim3(3, 1024), dim3(256), 0, stream>>>(
        NUS, ddW1t, d_dec_b1, Hd, HIDN, dec_tbl, NI, NI, (float*)nullptr, z, rowmap, cntpad);
    // D2 (compacted, scattered): out_x[rowmap[r]] = Hd @ W2t + b2
    k_mm<3><<<dim3(2, 1024), dim3(256), 0, stream>>>(
        Hd, ddW2t, d_dec_b2, out_x, MIDD, NF, NI, NI, (float*)nullptr, NF, rowmap, cntpad);
    k_tail<<<dim3(512), dim3(256), 0, stream>>>(ndec, out_b, out_m);
}

// Round 3
// 619.751 us; speedup vs baseline: 3.1273x; 1.0999x over previous
//
#include <hip/hip_runtime.h>

#define NPTS   65536
#define NB     2048
#define DIMX   256
#define HIDN   512
#define MAXNN  64
#define MIDK   288
#define MIDV   384
#define MIDD   384
#define MIDS   256

typedef unsigned short ushort_t;
typedef __attribute__((ext_vector_type(8))) short short8;
typedef __attribute__((ext_vector_type(4))) float f32x4;

// ---------------- helpers ----------------
__device__ __forceinline__ float mishf(float x) {
    float sp = (x > 20.f) ? x : log1pf(expf(x));
    return x * tanhf(sp);
}
__device__ __forceinline__ ushort_t f2bf(float f) {
    unsigned u = __float_as_uint(f);
    u += 0x7fffu + ((u >> 16) & 1u);
    return (ushort_t)(u >> 16);
}
__device__ __forceinline__ float bf2f(ushort_t h) {
    return __uint_as_float(((unsigned)h) << 16);
}
__device__ __forceinline__ void dma16(const void* g, void* lds) {
    __builtin_amdgcn_global_load_lds(
        (const __attribute__((address_space(1))) unsigned int*)g,
        (__attribute__((address_space(3))) unsigned int*)lds, 16, 0, 0);
}

// ---------------- small kernels ----------------
__global__ __launch_bounds__(256)
void k_starts(const int* __restrict__ batch, int* __restrict__ starts,
              unsigned int* __restrict__ maxmag, int* __restrict__ cnt)
{
    int b = blockIdx.x * blockDim.x + threadIdx.x;
    if (b == 0) { *maxmag = 0u; *cnt = 0; }
    if (b <= NB) {
        int lo = 0, hi = NPTS;
        while (lo < hi) { int mid = (lo + hi) >> 1; if (batch[mid] < b) lo = mid + 1; else hi = mid; }
        starts[b] = lo;
    }
}

__global__ __launch_bounds__(256)
void k_mag(const float* __restrict__ x, const float* __restrict__ rW,
           const float* __restrict__ rb, float* __restrict__ mag,
           unsigned int* __restrict__ maxmag, ushort_t* __restrict__ xb)
{
    const int lane = threadIdx.x & 63;
    const int wave = threadIdx.x >> 6;
    const int gw = blockIdx.x * 4 + wave;
    float4 wv = *(const float4*)(rW + lane * 4);
    float bias = rb[0];
    float lmax = 0.f;
    for (int pt = gw; pt < NPTS; pt += 4096) {
        float4 xv = *(const float4*)(x + (size_t)pt * DIMX + lane * 4);
        ushort4 u;
        u.x = f2bf(xv.x); u.y = f2bf(xv.y); u.z = f2bf(xv.z); u.w = f2bf(xv.w);
        *(ushort4*)(xb + (size_t)pt * DIMX + lane * 4) = u;
        double d = (double)xv.x * wv.x + (double)xv.y * wv.y
                 + (double)xv.z * wv.z + (double)xv.w * wv.w;
        #pragma unroll
        for (int o = 32; o > 0; o >>= 1) d += __shfl_xor(d, o);
        float s = fabsf((float)(d + (double)bias));
        if (lane == 0) mag[pt] = s;
        lmax = fmaxf(lmax, s);
    }
    __shared__ float wm[4];
    if (lane == 0) wm[wave] = lmax;
    __syncthreads();
    if (threadIdx.x == 0) {
        float m = fmaxf(fmaxf(wm[0], wm[1]), fmaxf(wm[2], wm[3]));
        atomicMax(maxmag, __float_as_uint(m));
    }
}

__global__ __launch_bounds__(256)
void k_rank(const int* __restrict__ batch, const int* __restrict__ starts,
            const float* __restrict__ mag, const unsigned int* __restrict__ maxmag,
            int* __restrict__ kidx)
{
    int i = blockIdx.x * 256 + threadIdx.x;
    if (i >= NPTS) return;
    int b = batch[i];
    int s = starts[b], e = starts[b + 1];
    float M = __uint_as_float(*maxmag);
    float kb = __fmul_rn((float)b, M);
    float ki = __fadd_rn(kb, mag[i]);
    int r = 0;
    for (int j = s; j < e; ++j) {
        float kj = __fadd_rn(kb, mag[j]);
        r += (kj < ki) || (kj == ki && j < i);
    }
    kidx[i] = (r < MAXNN) ? r : MAXNN;
}

__global__ __launch_bounds__(512)
void k_table(const float* __restrict__ W1, const float* __restrict__ b1,
             const float* __restrict__ g, const float* __restrict__ be,
             const float* __restrict__ W2, const float* __restrict__ b2,
             float* __restrict__ tbl, int in_dim, int n_w1_rows)
{
    const int row = blockIdx.x;
    const int t = threadIdx.x;
    __shared__ float h[MIDK];
    __shared__ float red[512];
    float v = 0.f;
    if (t < in_dim) v = b1[t] + (row < n_w1_rows ? W1[row * in_dim + t] : 0.f);
    red[t] = (t < in_dim) ? v : 0.f;
    __syncthreads();
    for (int o = 256; o > 0; o >>= 1) { if (t < o) red[t] += red[t + o]; __syncthreads(); }
    float m = red[0] / (float)in_dim;
    __syncthreads();
    float d = v - m;
    red[t] = (t < in_dim) ? d * d : 0.f;
    __syncthreads();
    for (int o = 256; o > 0; o >>= 1) { if (t < o) red[t] += red[t + o]; __syncthreads(); }
    float rs = rsqrtf(red[0] / (float)in_dim + 1e-5f);
    __syncthreads();
    if (t < in_dim) h[t] = mishf(d * rs * g[t] + be[t]);
    __syncthreads();
    float acc = b2[t];
    for (int k = 0; k < in_dim; ++k) acc = fmaf(h[k], W2[k * HIDN + t], acc);
    tbl[row * HIDN + t] = acc;
}

__global__ __launch_bounds__(256)
void k_card(const int* __restrict__ starts, const float* __restrict__ cardW,
            const float* __restrict__ cardb, float* __restrict__ z)
{
    int idx = blockIdx.x * 256 + threadIdx.x;
    int b = idx >> 9, c = idx & 511;
    float n = (float)(starts[b + 1] - starts[b]);
    z[idx] = fmaf(n, cardW[c], cardb[c]);
}

// LayerNorm + mish, one wave per row of [NPTS, 384] bf16, shuffle reductions.
__global__ __launch_bounds__(256)
void k_lnmish(ushort_t* __restrict__ H, const float* __restrict__ g,
              const float* __restrict__ be)
{
    const int l = threadIdx.x & 63;
    const int w = threadIdx.x >> 6;
    const int row = blockIdx.x * 4 + w;
    ushort_t* p = H + (size_t)row * MIDV + l * 6;
    unsigned u0 = *(const unsigned*)p;
    unsigned u1 = *(const unsigned*)(p + 2);
    unsigned u2 = *(const unsigned*)(p + 4);
    float v[6];
    v[0] = bf2f((ushort_t)u0); v[1] = bf2f((ushort_t)(u0 >> 16));
    v[2] = bf2f((ushort_t)u1); v[3] = bf2f((ushort_t)(u1 >> 16));
    v[4] = bf2f((ushort_t)u2); v[5] = bf2f((ushort_t)(u2 >> 16));
    float s = v[0] + v[1] + v[2] + v[3] + v[4] + v[5];
    #pragma unroll
    for (int o = 32; o > 0; o >>= 1) s += __shfl_xor(s, o);
    float m = s * (1.f / 384.f);
    float q = 0.f;
    #pragma unroll
    for (int i = 0; i < 6; ++i) { float d = v[i] - m; q += d * d; }
    #pragma unroll
    for (int o = 32; o > 0; o >>= 1) q += __shfl_xor(q, o);
    float rs = rsqrtf(q * (1.f / 384.f) + 1e-5f);
    ushort_t o6[6];
    #pragma unroll
    for (int i = 0; i < 6; ++i)
        o6[i] = f2bf(mishf((v[i] - m) * rs * g[l * 6 + i] + be[l * 6 + i]));
    *(unsigned*)p       = (unsigned)o6[0] | ((unsigned)o6[1] << 16);
    *(unsigned*)(p + 2) = (unsigned)o6[2] | ((unsigned)o6[3] << 16);
    *(unsigned*)(p + 4) = (unsigned)o6[4] | ((unsigned)o6[5] << 16);
}

// d_size MLP: 4 batches per block (4x W1 reuse)
__global__ __launch_bounds__(256)
void k_size(const float* __restrict__ z, const float* __restrict__ W1,
            const float* __restrict__ b1, const float* __restrict__ g,
            const float* __restrict__ be, const float* __restrict__ W2,
            const float* __restrict__ b2, int* __restrict__ ndec)
{
    const int b0 = blockIdx.x * 4, t = threadIdx.x;
    __shared__ float zr[4][HIDN];
    __shared__ float red[4][256];
    #pragma unroll
    for (int gI = 0; gI < 4; ++gI) {
        zr[gI][t] = z[(b0 + gI) * HIDN + t];
        zr[gI][t + 256] = z[(b0 + gI) * HIDN + 256 + t];
    }
    __syncthreads();
    float acc[4];
    float bb1 = b1[t];
    #pragma unroll
    for (int gI = 0; gI < 4; ++gI) acc[gI] = bb1;
    for (int k = 0; k < HIDN; ++k) {
        float wv = W1[k * MIDS + t];
        #pragma unroll
        for (int gI = 0; gI < 4; ++gI) acc[gI] = fmaf(zr[gI][k], wv, acc[gI]);
    }
    #pragma unroll
    for (int gI = 0; gI < 4; ++gI) red[gI][t] = acc[gI];
    __syncthreads();
    for (int o = 128; o > 0; o >>= 1) {
        if (t < o) {
            #pragma unroll
            for (int gI = 0; gI < 4; ++gI) red[gI][t] += red[gI][t + o];
        }
        __syncthreads();
    }
    float mm[4];
    #pragma unroll
    for (int gI = 0; gI < 4; ++gI) mm[gI] = red[gI][0] * (1.f / 256.f);
    __syncthreads();
    #pragma unroll
    for (int gI = 0; gI < 4; ++gI) { float d = acc[gI] - mm[gI]; red[gI][t] = d * d; }
    __syncthreads();
    for (int o = 128; o > 0; o >>= 1) {
        if (t < o) {
            #pragma unroll
            for (int gI = 0; gI < 4; ++gI) red[gI][t] += red[gI][t + o];
        }
        __syncthreads();
    }
    float rs[4];
    #pragma unroll
    for (int gI = 0; gI < 4; ++gI) rs[gI] = rsqrtf(red[gI][0] * (1.f / 256.f) + 1e-5f);
    __syncthreads();
    float w2 = W2[t], gg = g[t], bbe = be[t];
    #pragma unroll
    for (int gI = 0; gI < 4; ++gI) {
        float h = mishf((acc[gI] - mm[gI]) * rs[gI] * gg + bbe);
        red[gI][t] = h * w2;
    }
    __syncthreads();
    for (int o = 128; o > 0; o >>= 1) {
        if (t < o) {
            #pragma unroll
            for (int gI = 0; gI < 4; ++gI) red[gI][t] += red[gI][t + o];
        }
        __syncthreads();
    }
    if (t < 4) {
        float logit = red[t][0] + b2[0];
        float n = rintf(logit);
        n = fminf(fmaxf(n, 0.f), 64.f);
        ndec[b0 + t] = (int)n;
    }
}

__global__ __launch_bounds__(256)
void k_compact(const int* __restrict__ ndec, int* __restrict__ cnt,
               int* __restrict__ rowmap)
{
    int b = blockIdx.x * 256 + threadIdx.x;
    if (b >= NB) return;
    int n = ndec[b];
    if (n > 0) {
        int base = atomicAdd(cnt, n);
        for (int p = 0; p < n; ++p) rowmap[base + p] = b * 64 + p;
    }
}

__global__ __launch_bounds__(128)
void k_pad(const int* __restrict__ cnt, int* __restrict__ cntpad,
           int* __restrict__ rowmap)
{
    int c = *cnt;
    int pad = (c + 127) & ~127;
    int t = threadIdx.x;
    if (c + t < pad) rowmap[c + t] = -1;
    if (t == 0) *cntpad = pad;
}

__global__ __launch_bounds__(256)
void k_tail(const int* __restrict__ ndec, float* __restrict__ outb,
            float* __restrict__ outm)
{
    int r = blockIdx.x * 256 + threadIdx.x;
    if (r < NB * MAXNN) {
        outb[r] = (float)(r >> 6);
        outm[r] = ((r & 63) < ndec[r >> 6]) ? 1.f : 0.f;
    }
}

// all 4 weight transposes in one launch
__global__ __launch_bounds__(256)
void k_wt_all(const float* __restrict__ W0, ushort_t* __restrict__ T0,
              const float* __restrict__ W1s, ushort_t* __restrict__ T1,
              const float* __restrict__ W2s, ushort_t* __restrict__ T2,
              const float* __restrict__ W3s, ushort_t* __restrict__ T3)
{
    int idx = blockIdx.x * 256 + threadIdx.x;
    const float* W; ushort_t* T; int N, K, off;
    if (idx < 98304)       { W = W0;  T = T0; K = 256; N = 384; off = idx; }
    else if (idx < 294912) { W = W1s; T = T1; K = 384; N = 512; off = idx - 98304; }
    else if (idx < 491520) { W = W2s; T = T2; K = 512; N = 384; off = idx - 294912; }
    else                   { W = W3s; T = T3; K = 384; N = 256; off = idx - 491520; }
    int k = off / N, n = off - k * N;
    T[(size_t)n * K + k] = f2bf(W[off]);
}

// ---------------- MFMA GEMM body ----------------
// 128x128 tile, BK=64, XCD-swizzled block mapping, XOR-swizzled LDS.
// MODE 0 (E1): C=Hb bf16 <- A @ Bt + bias          (row stride MIDV)
// MODE 1 (E2): LDS segmented reduction -> atomicAdd z[batch] (one per run)
// MODE 2 (D1): A=z[rm>>6]*dec_tbl[rm&63] on the fly; C bf16 <- mish(.)  (stride MIDD)
// MODE 3 (D2): scatter C f32: out_x[rowmap[r]] <- A @ Bt + bias         (stride DIMX)
template<int MODE>
__device__ __forceinline__
void mm_body(const ushort_t* __restrict__ A, const ushort_t* __restrict__ Bt,
             const float* __restrict__ bias, void* __restrict__ Cptr, int K,
             const float* __restrict__ tbl, const int* __restrict__ kidx,
             const int* __restrict__ batch, float* __restrict__ zout,
             const float* __restrict__ zin, const int* __restrict__ rowmap,
             const int* __restrict__ cntpad)
{
    // XCD-aware swizzle: same-m tiles adjacent on one XCD (L2 A-reuse)
    const int flat = blockIdx.y * gridDim.x + blockIdx.x;
    const int nx = gridDim.x;
    const int xcd = flat & 7;
    const int lin = flat >> 3;
    const int n0 = (lin % nx) * 128;
    const int m0 = ((lin / nx) + ((gridDim.y >> 3) * xcd)) * 128;
    if (MODE >= 2) {
        if (m0 >= *cntpad) return;
    }
    __shared__ __align__(16) ushort_t sAB[2 * 128 * 64];
    ushort_t* As = sAB;
    ushort_t* Bs = sAB + 128 * 64;
    const int t = threadIdx.x;
    const int l = t & 63;
    const int w = t >> 6;
    const int wm = (w >> 1) * 64;
    const int wn = (w & 1) * 64;
    const int l4 = (l >> 4) << 2;
    const int drow = l >> 3;
    const int dblk = (l & 7) ^ drow;

    int g4[4], p4[4];
    if (MODE == 2) {
        #pragma unroll
        for (int ii = 0; ii < 4; ++ii) {
            int i = w * 4 + ii;
            int gr = rowmap[m0 + i * 8 + drow];
            if (gr < 0) gr = 0;
            g4[ii] = gr >> 6; p4[ii] = gr & 63;
        }
    }

    f32x4 acc[4][4];
    #pragma unroll
    for (int a = 0; a < 4; ++a)
        #pragma unroll
        for (int b = 0; b < 4; ++b) acc[a][b] = (f32x4)0.f;

    for (int k0 = 0; k0 < K; k0 += 64) {
        if (MODE == 2) {
            #pragma unroll
            for (int ii = 0; ii < 4; ++ii) {
                int i = w * 4 + ii;
                int row = i * 8 + drow;
                const float* zp = zin + g4[ii] * HIDN + k0 + dblk * 8;
                const float* kp = tbl + p4[ii] * HIDN + k0 + dblk * 8;
                float4 z0 = *(const float4*)zp;
                float4 z1 = *(const float4*)(zp + 4);
                float4 q0 = *(const float4*)kp;
                float4 q1 = *(const float4*)(kp + 4);
                ushort4 u0, u1;
                u0.x = f2bf(z0.x * q0.x); u0.y = f2bf(z0.y * q0.y);
                u0.z = f2bf(z0.z * q0.z); u0.w = f2bf(z0.w * q0.w);
                u1.x = f2bf(z1.x * q1.x); u1.y = f2bf(z1.y * q1.y);
                u1.z = f2bf(z1.z * q1.z); u1.w = f2bf(z1.w * q1.w);
                ushort_t* dst = &As[row * 64 + (l & 7) * 8];
                *(ushort4*)dst = u0;
                *(ushort4*)(dst + 4) = u1;
            }
        } else {
            #pragma unroll
            for (int ii = 0; ii < 4; ++ii) {
                int i = w * 4 + ii;
                const ushort_t* g = A + (size_t)(m0 + i * 8 + drow) * K + k0 + dblk * 8;
                dma16(g, &As[i * 512]);
            }
        }
        #pragma unroll
        for (int ii = 0; ii < 4; ++ii) {
            int i = w * 4 + ii;
            const ushort_t* g = Bt + (size_t)(n0 + i * 8 + drow) * K + k0 + dblk * 8;
            dma16(g, &Bs[i * 512]);
        }
        __syncthreads();
        #pragma unroll
        for (int ks = 0; ks < 2; ++ks) {
            short8 af[4], bfr[4];
            int kq = ks * 4 + (l >> 4);
            #pragma unroll
            for (int fm = 0; fm < 4; ++fm) {
                int row = wm + fm * 16 + (l & 15);
                af[fm] = *(const short8*)&As[row * 64 + ((kq ^ (row & 7)) << 3)];
            }
            #pragma unroll
            for (int fn = 0; fn < 4; ++fn) {
                int row = wn + fn * 16 + (l & 15);
                bfr[fn] = *(const short8*)&Bs[row * 64 + ((kq ^ (row & 7)) << 3)];
            }
            #pragma unroll
            for (int fm = 0; fm < 4; ++fm)
                #pragma unroll
                for (int fn = 0; fn < 4; ++fn)
                    acc[fm][fn] = __builtin_amdgcn_mfma_f32_16x16x32_bf16(
                        af[fm], bfr[fn], acc[fm][fn], 0, 0, 0);
        }
        __syncthreads();
    }

    if (MODE == 0) {
        ushort_t* C = (ushort_t*)Cptr;
        #pragma unroll
        for (int fm = 0; fm < 4; ++fm) {
            int gr0 = m0 + wm + fm * 16 + l4;
            #pragma unroll
            for (int fn = 0; fn < 4; ++fn) {
                int gc = n0 + wn + fn * 16 + (l & 15);
                float bb = bias[gc];
                #pragma unroll
                for (int j = 0; j < 4; ++j)
                    C[(size_t)(gr0 + j) * MIDV + gc] = f2bf(acc[fm][fn][j] + bb);
            }
        }
    } else if (MODE == 1) {
        // LDS segmented reduction epilogue
        __shared__ int barr[128];
        __shared__ int karr[128];
        float* yred = (float*)sAB;    // 64 rows x 128 cols f32, bank-swizzled
        if (t < 128) { barr[t] = batch[m0 + t]; karr[t] = kidx[m0 + t]; }
        __syncthreads();
        #pragma unroll
        for (int pass = 0; pass < 2; ++pass) {
            if (wm == pass * 64) {
                #pragma unroll
                for (int fn = 0; fn < 4; ++fn) {
                    int cl = wn + fn * 16 + (l & 15);
                    float bb = bias[n0 + cl];
                    #pragma unroll
                    for (int fm = 0; fm < 4; ++fm) {
                        #pragma unroll
                        for (int j = 0; j < 4; ++j) {
                            int rl = fm * 16 + l4 + j;        // 0..63
                            float v = (acc[fm][fn][j] + bb)
                                    * tbl[karr[pass * 64 + rl] * HIDN + (n0 + cl)];
                            yred[cl * 64 + (rl ^ (cl & 31))] = v;
                        }
                    }
                }
            }
            __syncthreads();
            {
                int c = t & 127, half = t >> 7;
                int gc = n0 + c;
                float run = 0.f; int curb = -1;
                #pragma unroll 1
                for (int rr = 0; rr < 32; ++rr) {
                    int rl = half * 32 + rr;
                    int b = barr[pass * 64 + rl];
                    float v = yred[c * 64 + (rl ^ (c & 31))];
                    if (b != curb) {
                        if (curb >= 0) atomicAdd(&zout[curb * HIDN + gc], run);
                        curb = b; run = v;
                    } else run += v;
                }
                atomicAdd(&zout[curb * HIDN + gc], run);
            }
            __syncthreads();
        }
    } else if (MODE == 2) {
        ushort_t* C = (ushort_t*)Cptr;
        #pragma unroll
        for (int fm = 0; fm < 4; ++fm) {
            int gr0 = m0 + wm + fm * 16 + l4;
            #pragma unroll
            for (int fn = 0; fn < 4; ++fn) {
                int gc = n0 + wn + fn * 16 + (l & 15);
                float bb = bias[gc];
                #pragma unroll
                for (int j = 0; j < 4; ++j)
                    C[(size_t)(gr0 + j) * MIDD + gc] = f2bf(mishf(acc[fm][fn][j] + bb));
            }
        }
    } else {
        float* C = (float*)Cptr;
        #pragma unroll
        for (int fm = 0; fm < 4; ++fm) {
            int gr0 = m0 + wm + fm * 16 + l4;
            int om[4];
            #pragma unroll
            for (int j = 0; j < 4; ++j) om[j] = rowmap[gr0 + j];
            #pragma unroll
            for (int fn = 0; fn < 4; ++fn) {
                int gc = n0 + wn + fn * 16 + (l & 15);
                float bb = bias[gc];
                #pragma unroll
                for (int j = 0; j < 4; ++j)
                    if (om[j] >= 0) C[(size_t)om[j] * DIMX + gc] = acc[fm][fn][j] + bb;
            }
        }
    }
}

__global__ __launch_bounds__(256, 2)
void k_mm_e1(const ushort_t* A, const ushort_t* Bt, const float* bias, void* C, int K)
{ mm_body<0>(A, Bt, bias, C, K, nullptr, nullptr, nullptr, nullptr, nullptr, nullptr, nullptr); }

__global__ __launch_bounds__(256, 2)
void k_mm_e2(const ushort_t* A, const ushort_t* Bt, const float* bias, int K,
             const float* tbl, const int* kidx, const int* batch, float* zout)
{ mm_body<1>(A, Bt, bias, nullptr, K, tbl, kidx, batch, zout, nullptr, nullptr, nullptr); }

__global__ __launch_bounds__(256, 2)
void k_mm_d1(const ushort_t* Bt, const float* bias, void* C, int K,
             const float* tbl, const float* zin, const int* rowmap, const int* cntpad)
{ mm_body<2>(nullptr, Bt, bias, C, K, tbl, nullptr, nullptr, nullptr, zin, rowmap, cntpad); }

__global__ __launch_bounds__(256, 2)
void k_mm_d2(const ushort_t* A, const ushort_t* Bt, const float* bias, void* C, int K,
             const int* rowmap, const int* cntpad)
{ mm_body<3>(A, Bt, bias, C, K, nullptr, nullptr, nullptr, nullptr, nullptr, rowmap, cntpad); }

// ---------------- launch ----------------
extern "C" void kernel_launch(void* const* d_in, const int* in_sizes, int n_in,
                              void* d_out, int out_size, void* d_ws, size_t ws_size,
                              hipStream_t stream)
{
    const float* x        = (const float*)d_in[0];
    const int*   batch    = (const int*)  d_in[1];
    const float* e_rank_W = (const float*)d_in[3];
    const float* e_rank_b = (const float*)d_in[4];
    const float* e_card_W = (const float*)d_in[5];
    const float* e_card_b = (const float*)d_in[6];
    const float* e_key_W1 = (const float*)d_in[7];
    const float* e_key_b1 = (const float*)d_in[8];
    const float* e_key_g  = (const float*)d_in[9];
    const float* e_key_be = (const float*)d_in[10];
    const float* e_key_W2 = (const float*)d_in[11];
    const float* e_key_b2 = (const float*)d_in[12];
    const float* e_val_W1 = (const float*)d_in[13];
    const float* e_val_b1 = (const float*)d_in[14];
    const float* e_val_g  = (const float*)d_in[15];
    const float* e_val_be = (const float*)d_in[16];
    const float* e_val_W2 = (const float*)d_in[17];
    const float* e_val_b2 = (const float*)d_in[18];
    const float* d_key_W1 = (const float*)d_in[19];
    const float* d_key_b1 = (const float*)d_in[20];
    const float* d_key_g  = (const float*)d_in[21];
    const float* d_key_be = (const float*)d_in[22];
    const float* d_key_W2 = (const float*)d_in[23];
    const float* d_key_b2 = (const float*)d_in[24];
    const float* d_dec_W1 = (const float*)d_in[25];
    const float* d_dec_b1 = (const float*)d_in[26];
    const float* d_dec_W2 = (const float*)d_in[27];
    const float* d_dec_b2 = (const float*)d_in[28];
    const float* d_size_W1= (const float*)d_in[29];
    const float* d_size_b1= (const float*)d_in[30];
    const float* d_size_g = (const float*)d_in[31];
    const float* d_size_be= (const float*)d_in[32];
    const float* d_size_W2= (const float*)d_in[33];
    const float* d_size_b2= (const float*)d_in[34];

    char* ws = (char*)d_ws;
    int*          starts  = (int*)         (ws + 0);
    unsigned int* maxmag  = (unsigned int*)(ws + 8448);
    int*          kidx    = (int*)         (ws + 8704);
    float*        mag     = (float*)       (ws + 270848);
    float*        enc_tbl = (float*)       (ws + 532992);
    float*        dec_tbl = (float*)       (ws + 666112);
    float*        z       = (float*)       (ws + 797184);
    int*          ndec    = (int*)         (ws + 4991488);
    int*          cnt     = (int*)         (ws + 4999680);
    int*          cntpad  = (int*)         (ws + 4999684);
    int*          rowmap  = (int*)         (ws + 5000192);
    ushort_t*     evW1t   = (ushort_t*)    (ws + 5524480);
    ushort_t*     evW2t   = (ushort_t*)    (ws + 5721088);
    ushort_t*     ddW1t   = (ushort_t*)    (ws + 6114304);
    ushort_t*     ddW2t   = (ushort_t*)    (ws + 6507520);
    ushort_t*     xb      = (ushort_t*)    (ws + 6704384);
    ushort_t*     Hb      = (ushort_t*)    (ws + 6704384 + 33554432);
    ushort_t*     Hd      = (ushort_t*)    (ws + 6704384);

    float* out_x = (float*)d_out;
    float* out_b = out_x + (size_t)NB * MAXNN * DIMX;
    float* out_m = out_b + NB * MAXNN;

    k_starts<<<dim3(9), dim3(256), 0, stream>>>(batch, starts, maxmag, cnt);
    k_mag<<<dim3(1024), dim3(256), 0, stream>>>(x, e_rank_W, e_rank_b, mag, maxmag, xb);
    k_rank<<<dim3(256), dim3(256), 0, stream>>>(batch, starts, mag, maxmag, kidx);
    k_table<<<dim3(65), dim3(512), 0, stream>>>(e_key_W1, e_key_b1, e_key_g, e_key_be,
                                                e_key_W2, e_key_b2, enc_tbl, MIDK, 64);
    k_table<<<dim3(64), dim3(512), 0, stream>>>(d_key_W1, d_key_b1, d_key_g, d_key_be,
                                                d_key_W2, d_key_b2, dec_tbl, MIDK, 64);
    k_card<<<dim3(4096), dim3(256), 0, stream>>>(starts, e_card_W, e_card_b, z);
    k_wt_all<<<dim3(2304), dim3(256), 0, stream>>>(e_val_W1, evW1t, e_val_W2, evW2t,
                                                   d_dec_W1, ddW1t, d_dec_W2, ddW2t);

    k_mm_e1<<<dim3(3, 512), dim3(256), 0, stream>>>(xb, evW1t, e_val_b1, Hb, DIMX);
    k_lnmish<<<dim3(NPTS / 4), dim3(256), 0, stream>>>(Hb, e_val_g, e_val_be);
    k_mm_e2<<<dim3(4, 512), dim3(256), 0, stream>>>(Hb, evW2t, e_val_b2, MIDV,
                                                    enc_tbl, kidx, batch, z);
    k_size<<<dim3(NB / 4), dim3(256), 0, stream>>>(z, d_size_W1, d_size_b1, d_size_g,
                                                   d_size_be, d_size_W2, d_size_b2, ndec);
    k_compact<<<dim3(8), dim3(256), 0, stream>>>(ndec, cnt, rowmap);
    k_pad<<<dim3(1), dim3(128), 0, stream>>>(cnt, cntpad, rowmap);
    hipMemsetAsync(out_x, 0, (size_t)NB * MAXNN * DIMX * sizeof(float), stream);
    k_mm_d1<<<dim3(3, 1024), dim3(256), 0, stream>>>(ddW1t, d_dec_b1, Hd, HIDN,
                                                     dec_tbl, z, rowmap, cntpad);
    k_mm_d2<<<dim3(2, 1024), dim3(256), 0, stream>>>(Hd, ddW2t, d_dec_b2, out_x, MIDD,
                                                     rowmap, cntpad);
    k_tail<<<dim3(512), dim3(256), 0, stream>>>(ndec, out_b, out_m);
}

// Round 4
// 506.081 us; speedup vs baseline: 3.8298x; 1.2246x over previous
//
#include <hip/hip_runtime.h>

#define NPTS   65536
#define NB     2048
#define DIMX   256
#define HIDN   512
#define MAXNN  64
#define MIDK   288
#define MIDV   384
#define MIDD   384
#define MIDS   256

typedef unsigned short ushort_t;
typedef __attribute__((ext_vector_type(8))) short short8;
typedef __attribute__((ext_vector_type(4))) float f32x4;

// ---------------- helpers ----------------
// mish(x) = x*tanh(softplus(x)) = x * e(e+2)/(e(e+2)+2), e = exp(x)  [exact identity]
__device__ __forceinline__ float mishf(float x) {
    float e = __expf(fminf(x, 30.f));
    float n = e * (e + 2.f);
    return x * n * __builtin_amdgcn_rcpf(n + 2.f);
}
__device__ __forceinline__ ushort_t f2bf(float f) {
    unsigned u = __float_as_uint(f);
    u += 0x7fffu + ((u >> 16) & 1u);
    return (ushort_t)(u >> 16);
}
__device__ __forceinline__ float bf2f(ushort_t h) {
    return __uint_as_float(((unsigned)h) << 16);
}
__device__ __forceinline__ void dma16(const void* g, void* lds) {
    __builtin_amdgcn_global_load_lds(
        (const __attribute__((address_space(1))) unsigned int*)g,
        (__attribute__((address_space(3))) unsigned int*)lds, 16, 0, 0);
}

// ---------------- small kernels ----------------
__global__ __launch_bounds__(256)
void k_starts(const int* __restrict__ batch, int* __restrict__ starts,
              unsigned int* __restrict__ maxmag, int* __restrict__ cnt)
{
    int b = blockIdx.x * blockDim.x + threadIdx.x;
    if (b == 0) { *maxmag = 0u; *cnt = 0; }
    if (b <= NB) {
        int lo = 0, hi = NPTS;
        while (lo < hi) { int mid = (lo + hi) >> 1; if (batch[mid] < b) lo = mid + 1; else hi = mid; }
        starts[b] = lo;
    }
}

__global__ __launch_bounds__(256)
void k_mag(const float* __restrict__ x, const float* __restrict__ rW,
           const float* __restrict__ rb, float* __restrict__ mag,
           unsigned int* __restrict__ maxmag, ushort_t* __restrict__ xb)
{
    const int lane = threadIdx.x & 63;
    const int wave = threadIdx.x >> 6;
    const int gw = blockIdx.x * 4 + wave;
    float4 wv = *(const float4*)(rW + lane * 4);
    float bias = rb[0];
    float lmax = 0.f;
    for (int pt = gw; pt < NPTS; pt += 4096) {
        float4 xv = *(const float4*)(x + (size_t)pt * DIMX + lane * 4);
        ushort4 u;
        u.x = f2bf(xv.x); u.y = f2bf(xv.y); u.z = f2bf(xv.z); u.w = f2bf(xv.w);
        *(ushort4*)(xb + (size_t)pt * DIMX + lane * 4) = u;
        double d = (double)xv.x * wv.x + (double)xv.y * wv.y
                 + (double)xv.z * wv.z + (double)xv.w * wv.w;
        #pragma unroll
        for (int o = 32; o > 0; o >>= 1) d += __shfl_xor(d, o);
        float s = fabsf((float)(d + (double)bias));
        if (lane == 0) mag[pt] = s;
        lmax = fmaxf(lmax, s);
    }
    __shared__ float wm[4];
    if (lane == 0) wm[wave] = lmax;
    __syncthreads();
    if (threadIdx.x == 0) {
        float m = fmaxf(fmaxf(wm[0], wm[1]), fmaxf(wm[2], wm[3]));
        atomicMax(maxmag, __float_as_uint(m));
    }
}

__global__ __launch_bounds__(256)
void k_rank(const int* __restrict__ batch, const int* __restrict__ starts,
            const float* __restrict__ mag, const unsigned int* __restrict__ maxmag,
            int* __restrict__ kidx)
{
    int i = blockIdx.x * 256 + threadIdx.x;
    if (i >= NPTS) return;
    int b = batch[i];
    int s = starts[b], e = starts[b + 1];
    float M = __uint_as_float(*maxmag);
    float kb = __fmul_rn((float)b, M);
    float ki = __fadd_rn(kb, mag[i]);
    int r = 0;
    for (int j = s; j < e; ++j) {
        float kj = __fadd_rn(kb, mag[j]);
        r += (kj < ki) || (kj == ki && j < i);
    }
    kidx[i] = (r < MAXNN) ? r : MAXNN;
}

__global__ __launch_bounds__(512)
void k_table(const float* __restrict__ W1, const float* __restrict__ b1,
             const float* __restrict__ g, const float* __restrict__ be,
             const float* __restrict__ W2, const float* __restrict__ b2,
             float* __restrict__ tbl, int in_dim, int n_w1_rows)
{
    const int row = blockIdx.x;
    const int t = threadIdx.x;
    __shared__ float h[MIDK];
    __shared__ float red[512];
    float v = 0.f;
    if (t < in_dim) v = b1[t] + (row < n_w1_rows ? W1[row * in_dim + t] : 0.f);
    red[t] = (t < in_dim) ? v : 0.f;
    __syncthreads();
    for (int o = 256; o > 0; o >>= 1) { if (t < o) red[t] += red[t + o]; __syncthreads(); }
    float m = red[0] / (float)in_dim;
    __syncthreads();
    float d = v - m;
    red[t] = (t < in_dim) ? d * d : 0.f;
    __syncthreads();
    for (int o = 256; o > 0; o >>= 1) { if (t < o) red[t] += red[t + o]; __syncthreads(); }
    float rs = rsqrtf(red[0] / (float)in_dim + 1e-5f);
    __syncthreads();
    if (t < in_dim) h[t] = mishf(d * rs * g[t] + be[t]);
    __syncthreads();
    float acc = b2[t];
    for (int k = 0; k < in_dim; ++k) acc = fmaf(h[k], W2[k * HIDN + t], acc);
    tbl[row * HIDN + t] = acc;
}

__global__ __launch_bounds__(256)
void k_card(const int* __restrict__ starts, const float* __restrict__ cardW,
            const float* __restrict__ cardb, float* __restrict__ z)
{
    int idx = blockIdx.x * 256 + threadIdx.x;
    int b = idx >> 9, c = idx & 511;
    float n = (float)(starts[b + 1] - starts[b]);
    z[idx] = fmaf(n, cardW[c], cardb[c]);
}

// d_size MLP: 4 batches per block (4x W1 reuse)
__global__ __launch_bounds__(256)
void k_size(const float* __restrict__ z, const float* __restrict__ W1,
            const float* __restrict__ b1, const float* __restrict__ g,
            const float* __restrict__ be, const float* __restrict__ W2,
            const float* __restrict__ b2, int* __restrict__ ndec)
{
    const int b0 = blockIdx.x * 4, t = threadIdx.x;
    __shared__ float zr[4][HIDN];
    __shared__ float red[4][256];
    #pragma unroll
    for (int gI = 0; gI < 4; ++gI) {
        zr[gI][t] = z[(b0 + gI) * HIDN + t];
        zr[gI][t + 256] = z[(b0 + gI) * HIDN + 256 + t];
    }
    __syncthreads();
    float acc[4];
    float bb1 = b1[t];
    #pragma unroll
    for (int gI = 0; gI < 4; ++gI) acc[gI] = bb1;
    for (int k = 0; k < HIDN; ++k) {
        float wv = W1[k * MIDS + t];
        #pragma unroll
        for (int gI = 0; gI < 4; ++gI) acc[gI] = fmaf(zr[gI][k], wv, acc[gI]);
    }
    #pragma unroll
    for (int gI = 0; gI < 4; ++gI) red[gI][t] = acc[gI];
    __syncthreads();
    for (int o = 128; o > 0; o >>= 1) {
        if (t < o) {
            #pragma unroll
            for (int gI = 0; gI < 4; ++gI) red[gI][t] += red[gI][t + o];
        }
        __syncthreads();
    }
    float mm[4];
    #pragma unroll
    for (int gI = 0; gI < 4; ++gI) mm[gI] = red[gI][0] * (1.f / 256.f);
    __syncthreads();
    #pragma unroll
    for (int gI = 0; gI < 4; ++gI) { float d = acc[gI] - mm[gI]; red[gI][t] = d * d; }
    __syncthreads();
    for (int o = 128; o > 0; o >>= 1) {
        if (t < o) {
            #pragma unroll
            for (int gI = 0; gI < 4; ++gI) red[gI][t] += red[gI][t + o];
        }
        __syncthreads();
    }
    float rs[4];
    #pragma unroll
    for (int gI = 0; gI < 4; ++gI) rs[gI] = rsqrtf(red[gI][0] * (1.f / 256.f) + 1e-5f);
    __syncthreads();
    float w2 = W2[t], gg = g[t], bbe = be[t];
    #pragma unroll
    for (int gI = 0; gI < 4; ++gI) {
        float h = mishf((acc[gI] - mm[gI]) * rs[gI] * gg + bbe);
        red[gI][t] = h * w2;
    }
    __syncthreads();
    for (int o = 128; o > 0; o >>= 1) {
        if (t < o) {
            #pragma unroll
            for (int gI = 0; gI < 4; ++gI) red[gI][t] += red[gI][t + o];
        }
        __syncthreads();
    }
    if (t < 4) {
        float logit = red[t][0] + b2[0];
        float n = rintf(logit);
        n = fminf(fmaxf(n, 0.f), 64.f);
        ndec[b0 + t] = (int)n;
    }
}

__global__ __launch_bounds__(256)
void k_compact(const int* __restrict__ ndec, int* __restrict__ cnt,
               int* __restrict__ rowmap)
{
    int b = blockIdx.x * 256 + threadIdx.x;
    if (b >= NB) return;
    int n = ndec[b];
    if (n > 0) {
        int base = atomicAdd(cnt, n);
        for (int p = 0; p < n; ++p) rowmap[base + p] = b * 64 + p;
    }
}

__global__ __launch_bounds__(128)
void k_pad(const int* __restrict__ cnt, int* __restrict__ cntpad,
           int* __restrict__ rowmap)
{
    int c = *cnt;
    int pad = (c + 127) & ~127;
    int t = threadIdx.x;
    if (c + t < pad) rowmap[c + t] = -1;
    if (t == 0) *cntpad = pad;
}

__global__ __launch_bounds__(256)
void k_tail(const int* __restrict__ ndec, float* __restrict__ outb,
            float* __restrict__ outm)
{
    int r = blockIdx.x * 256 + threadIdx.x;
    if (r < NB * MAXNN) {
        outb[r] = (float)(r >> 6);
        outm[r] = ((r & 63) < ndec[r >> 6]) ? 1.f : 0.f;
    }
}

__global__ __launch_bounds__(256)
void k_wt_all(const float* __restrict__ W0, ushort_t* __restrict__ T0,
              const float* __restrict__ W1s, ushort_t* __restrict__ T1,
              const float* __restrict__ W2s, ushort_t* __restrict__ T2,
              const float* __restrict__ W3s, ushort_t* __restrict__ T3)
{
    int idx = blockIdx.x * 256 + threadIdx.x;
    const float* W; ushort_t* T; int N, K, off;
    if (idx < 98304)       { W = W0;  T = T0; K = 256; N = 384; off = idx; }
    else if (idx < 294912) { W = W1s; T = T1; K = 384; N = 512; off = idx - 98304; }
    else if (idx < 491520) { W = W2s; T = T2; K = 512; N = 384; off = idx - 294912; }
    else                   { W = W3s; T = T3; K = 384; N = 256; off = idx - 491520; }
    int k = off / N, n = off - k * N;
    T[(size_t)n * K + k] = f2bf(W[off]);
}

// ---------------- E1 fused: Hb = bf16(mish(LN(xb @ W1t + b1)))  ----------------
// 512 threads, 8 waves in 2(row)x4(col) layout; block computes full 128x384 slab.
__global__ __launch_bounds__(512, 2)
void k_mm_e1f(const ushort_t* __restrict__ A, const ushort_t* __restrict__ Bt,
              const float* __restrict__ bias, const float* __restrict__ g,
              const float* __restrict__ be, ushort_t* __restrict__ C)
{
    const int m0 = blockIdx.x * 128;
    __shared__ __align__(16) ushort_t As[128 * 64];    // 16 KB
    __shared__ __align__(16) ushort_t Bs[384 * 64];    // 48 KB
    const int t = threadIdx.x;
    const int l = t & 63;
    const int w = t >> 6;            // 0..7
    const int wm = (w >> 2) * 64;    // row half
    const int wq = (w & 3) * 96;     // col quarter (96 cols)
    const int l4 = (l >> 4) << 2;
    const int drow = l >> 3;
    const int dblk = (l & 7) ^ drow;

    f32x4 acc[4][6];
    #pragma unroll
    for (int a = 0; a < 4; ++a)
        #pragma unroll
        for (int b = 0; b < 6; ++b) acc[a][b] = (f32x4)0.f;

    for (int k0 = 0; k0 < DIMX; k0 += 64) {
        #pragma unroll
        for (int ii = 0; ii < 2; ++ii) {
            int i = w * 2 + ii;
            dma16(A + (size_t)(m0 + i * 8 + drow) * DIMX + k0 + dblk * 8, &As[i * 512]);
        }
        #pragma unroll
        for (int ii = 0; ii < 6; ++ii) {
            int i = w * 6 + ii;
            dma16(Bt + (size_t)(i * 8 + drow) * DIMX + k0 + dblk * 8, &Bs[i * 512]);
        }
        __syncthreads();
        #pragma unroll
        for (int ks = 0; ks < 2; ++ks) {
            int kq = ks * 4 + (l >> 4);
            short8 af[4], bfr[6];
            #pragma unroll
            for (int fm = 0; fm < 4; ++fm) {
                int row = wm + fm * 16 + (l & 15);
                af[fm] = *(const short8*)&As[row * 64 + ((kq ^ (row & 7)) << 3)];
            }
            #pragma unroll
            for (int fn = 0; fn < 6; ++fn) {
                int row = wq + fn * 16 + (l & 15);
                bfr[fn] = *(const short8*)&Bs[row * 64 + ((kq ^ (row & 7)) << 3)];
            }
            #pragma unroll
            for (int fm = 0; fm < 4; ++fm)
                #pragma unroll
                for (int fn = 0; fn < 6; ++fn)
                    acc[fm][fn] = __builtin_amdgcn_mfma_f32_16x16x32_bf16(
                        af[fm], bfr[fn], acc[fm][fn], 0, 0, 0);
        }
        __syncthreads();
    }

    // ---- fused bias + LayerNorm + mish + bf16 store ----
    float bb[6], gg[6], bee[6];
    #pragma unroll
    for (int fn = 0; fn < 6; ++fn) {
        int col = wq + fn * 16 + (l & 15);
        bb[fn] = bias[col]; gg[fn] = g[col]; bee[fn] = be[col];
    }
    #pragma unroll
    for (int fm = 0; fm < 4; ++fm)
        #pragma unroll
        for (int fn = 0; fn < 6; ++fn)
            #pragma unroll
            for (int j = 0; j < 4; ++j) acc[fm][fn][j] += bb[fn];

    float* ssum = (float*)As;          // [128][4]
    float* ssq  = ssum + 512;          // [128][4]
    #pragma unroll
    for (int fm = 0; fm < 4; ++fm) {
        #pragma unroll
        for (int j = 0; j < 4; ++j) {
            float s = 0.f, q = 0.f;
            #pragma unroll
            for (int fn = 0; fn < 6; ++fn) {
                float v = acc[fm][fn][j];
                s += v; q += v * v;
            }
            #pragma unroll
            for (int o = 1; o < 16; o <<= 1) {
                s += __shfl_xor(s, o);
                q += __shfl_xor(q, o);
            }
            if ((l & 15) == 0) {
                int r = wm + fm * 16 + l4 + j;
                ssum[r * 4 + (w & 3)] = s;
                ssq[r * 4 + (w & 3)] = q;
            }
        }
    }
    __syncthreads();
    #pragma unroll
    for (int fm = 0; fm < 4; ++fm) {
        #pragma unroll
        for (int j = 0; j < 4; ++j) {
            int r = wm + fm * 16 + l4 + j;
            float s = ssum[r * 4 + 0] + ssum[r * 4 + 1] + ssum[r * 4 + 2] + ssum[r * 4 + 3];
            float q = ssq[r * 4 + 0] + ssq[r * 4 + 1] + ssq[r * 4 + 2] + ssq[r * 4 + 3];
            float m = s * (1.f / 384.f);
            float var = q * (1.f / 384.f) - m * m;
            float rs = rsqrtf(var + 1e-5f);
            #pragma unroll
            for (int fn = 0; fn < 6; ++fn) {
                float v = (acc[fm][fn][j] - m) * rs * gg[fn] + bee[fn];
                C[(size_t)(m0 + r) * MIDV + wq + fn * 16 + (l & 15)] = f2bf(mishf(v));
            }
        }
    }
}

// ---------------- MFMA GEMM body (modes 1..3) ----------------
template<int MODE>
__device__ __forceinline__
void mm_body(const ushort_t* __restrict__ A, const ushort_t* __restrict__ Bt,
             const float* __restrict__ bias, void* __restrict__ Cptr, int K,
             const float* __restrict__ tbl, const int* __restrict__ kidx,
             const int* __restrict__ batch, float* __restrict__ zout,
             const float* __restrict__ zin, const int* __restrict__ rowmap,
             const int* __restrict__ cntpad)
{
    const int flat = blockIdx.y * gridDim.x + blockIdx.x;
    const int nx = gridDim.x;
    const int xcd = flat & 7;
    const int lin = flat >> 3;
    const int n0 = (lin % nx) * 128;
    const int m0 = ((lin / nx) + ((gridDim.y >> 3) * xcd)) * 128;
    if (MODE >= 2) {
        if (m0 >= *cntpad) return;
    }
    __shared__ __align__(16) ushort_t sAB[2 * 128 * 64];
    ushort_t* As = sAB;
    ushort_t* Bs = sAB + 128 * 64;
    const int t = threadIdx.x;
    const int l = t & 63;
    const int w = t >> 6;
    const int wm = (w >> 1) * 64;
    const int wn = (w & 1) * 64;
    const int l4 = (l >> 4) << 2;
    const int drow = l >> 3;
    const int dblk = (l & 7) ^ drow;

    int g4[4], p4[4];
    if (MODE == 2) {
        #pragma unroll
        for (int ii = 0; ii < 4; ++ii) {
            int i = w * 4 + ii;
            int gr = rowmap[m0 + i * 8 + drow];
            if (gr < 0) gr = 0;
            g4[ii] = gr >> 6; p4[ii] = gr & 63;
        }
    }

    f32x4 acc[4][4];
    #pragma unroll
    for (int a = 0; a < 4; ++a)
        #pragma unroll
        for (int b = 0; b < 4; ++b) acc[a][b] = (f32x4)0.f;

    for (int k0 = 0; k0 < K; k0 += 64) {
        if (MODE == 2) {
            #pragma unroll
            for (int ii = 0; ii < 4; ++ii) {
                int i = w * 4 + ii;
                int row = i * 8 + drow;
                const float* zp = zin + g4[ii] * HIDN + k0 + dblk * 8;
                const float* kp = tbl + p4[ii] * HIDN + k0 + dblk * 8;
                float4 z0 = *(const float4*)zp;
                float4 z1 = *(const float4*)(zp + 4);
                float4 q0 = *(const float4*)kp;
                float4 q1 = *(const float4*)(kp + 4);
                ushort4 u0, u1;
                u0.x = f2bf(z0.x * q0.x); u0.y = f2bf(z0.y * q0.y);
                u0.z = f2bf(z0.z * q0.z); u0.w = f2bf(z0.w * q0.w);
                u1.x = f2bf(z1.x * q1.x); u1.y = f2bf(z1.y * q1.y);
                u1.z = f2bf(z1.z * q1.z); u1.w = f2bf(z1.w * q1.w);
                ushort_t* dst = &As[row * 64 + (l & 7) * 8];
                *(ushort4*)dst = u0;
                *(ushort4*)(dst + 4) = u1;
            }
        } else {
            #pragma unroll
            for (int ii = 0; ii < 4; ++ii) {
                int i = w * 4 + ii;
                const ushort_t* g = A + (size_t)(m0 + i * 8 + drow) * K + k0 + dblk * 8;
                dma16(g, &As[i * 512]);
            }
        }
        #pragma unroll
        for (int ii = 0; ii < 4; ++ii) {
            int i = w * 4 + ii;
            const ushort_t* g = Bt + (size_t)(n0 + i * 8 + drow) * K + k0 + dblk * 8;
            dma16(g, &Bs[i * 512]);
        }
        __syncthreads();
        #pragma unroll
        for (int ks = 0; ks < 2; ++ks) {
            short8 af[4], bfr[4];
            int kq = ks * 4 + (l >> 4);
            #pragma unroll
            for (int fm = 0; fm < 4; ++fm) {
                int row = wm + fm * 16 + (l & 15);
                af[fm] = *(const short8*)&As[row * 64 + ((kq ^ (row & 7)) << 3)];
            }
            #pragma unroll
            for (int fn = 0; fn < 4; ++fn) {
                int row = wn + fn * 16 + (l & 15);
                bfr[fn] = *(const short8*)&Bs[row * 64 + ((kq ^ (row & 7)) << 3)];
            }
            #pragma unroll
            for (int fm = 0; fm < 4; ++fm)
                #pragma unroll
                for (int fn = 0; fn < 4; ++fn)
                    acc[fm][fn] = __builtin_amdgcn_mfma_f32_16x16x32_bf16(
                        af[fm], bfr[fn], acc[fm][fn], 0, 0, 0);
        }
        __syncthreads();
    }

    if (MODE == 1) {
        __shared__ int barr[128];
        __shared__ int karr[128];
        float* yred = (float*)sAB;
        if (t < 128) { barr[t] = batch[m0 + t]; karr[t] = kidx[m0 + t]; }
        __syncthreads();
        #pragma unroll
        for (int pass = 0; pass < 2; ++pass) {
            if (wm == pass * 64) {
                #pragma unroll
                for (int fn = 0; fn < 4; ++fn) {
                    int cl = wn + fn * 16 + (l & 15);
                    float bb = bias[n0 + cl];
                    #pragma unroll
                    for (int fm = 0; fm < 4; ++fm) {
                        #pragma unroll
                        for (int j = 0; j < 4; ++j) {
                            int rl = fm * 16 + l4 + j;
                            float v = (acc[fm][fn][j] + bb)
                                    * tbl[karr[pass * 64 + rl] * HIDN + (n0 + cl)];
                            yred[cl * 64 + (rl ^ (cl & 31))] = v;
                        }
                    }
                }
            }
            __syncthreads();
            {
                int c = t & 127, half = t >> 7;
                int gc = n0 + c;
                float run = 0.f; int curb = -1;
                #pragma unroll 1
                for (int rr = 0; rr < 32; ++rr) {
                    int rl = half * 32 + rr;
                    int b = barr[pass * 64 + rl];
                    float v = yred[c * 64 + (rl ^ (c & 31))];
                    if (b != curb) {
                        if (curb >= 0) atomicAdd(&zout[curb * HIDN + gc], run);
                        curb = b; run = v;
                    } else run += v;
                }
                atomicAdd(&zout[curb * HIDN + gc], run);
            }
            __syncthreads();
        }
    } else if (MODE == 2) {
        ushort_t* C = (ushort_t*)Cptr;
        #pragma unroll
        for (int fm = 0; fm < 4; ++fm) {
            int gr0 = m0 + wm + fm * 16 + l4;
            #pragma unroll
            for (int fn = 0; fn < 4; ++fn) {
                int gc = n0 + wn + fn * 16 + (l & 15);
                float bb = bias[gc];
                #pragma unroll
                for (int j = 0; j < 4; ++j)
                    C[(size_t)(gr0 + j) * MIDD + gc] = f2bf(mishf(acc[fm][fn][j] + bb));
            }
        }
    } else if (MODE == 3) {
        float* C = (float*)Cptr;
        #pragma unroll
        for (int fm = 0; fm < 4; ++fm) {
            int gr0 = m0 + wm + fm * 16 + l4;
            int om[4];
            #pragma unroll
            for (int j = 0; j < 4; ++j) om[j] = rowmap[gr0 + j];
            #pragma unroll
            for (int fn = 0; fn < 4; ++fn) {
                int gc = n0 + wn + fn * 16 + (l & 15);
                float bb = bias[gc];
                #pragma unroll
                for (int j = 0; j < 4; ++j)
                    if (om[j] >= 0) C[(size_t)om[j] * DIMX + gc] = acc[fm][fn][j] + bb;
            }
        }
    }
}

__global__ __launch_bounds__(256, 2)
void k_mm_e2(const ushort_t* A, const ushort_t* Bt, const float* bias, int K,
             const float* tbl, const int* kidx, const int* batch, float* zout)
{ mm_body<1>(A, Bt, bias, nullptr, K, tbl, kidx, batch, zout, nullptr, nullptr, nullptr); }

__global__ __launch_bounds__(256, 2)
void k_mm_d1(const ushort_t* Bt, const float* bias, void* C, int K,
             const float* tbl, const float* zin, const int* rowmap, const int* cntpad)
{ mm_body<2>(nullptr, Bt, bias, C, K, tbl, nullptr, nullptr, nullptr, zin, rowmap, cntpad); }

__global__ __launch_bounds__(256, 2)
void k_mm_d2(const ushort_t* A, const ushort_t* Bt, const float* bias, void* C, int K,
             const int* rowmap, const int* cntpad)
{ mm_body<3>(A, Bt, bias, C, K, nullptr, nullptr, nullptr, nullptr, nullptr, rowmap, cntpad); }

// ---------------- launch ----------------
extern "C" void kernel_launch(void* const* d_in, const int* in_sizes, int n_in,
                              void* d_out, int out_size, void* d_ws, size_t ws_size,
                              hipStream_t stream)
{
    const float* x        = (const float*)d_in[0];
    const int*   batch    = (const int*)  d_in[1];
    const float* e_rank_W = (const float*)d_in[3];
    const float* e_rank_b = (const float*)d_in[4];
    const float* e_card_W = (const float*)d_in[5];
    const float* e_card_b = (const float*)d_in[6];
    const float* e_key_W1 = (const float*)d_in[7];
    const float* e_key_b1 = (const float*)d_in[8];
    const float* e_key_g  = (const float*)d_in[9];
    const float* e_key_be = (const float*)d_in[10];
    const float* e_key_W2 = (const float*)d_in[11];
    const float* e_key_b2 = (const float*)d_in[12];
    const float* e_val_W1 = (const float*)d_in[13];
    const float* e_val_b1 = (const float*)d_in[14];
    const float* e_val_g  = (const float*)d_in[15];
    const float* e_val_be = (const float*)d_in[16];
    const float* e_val_W2 = (const float*)d_in[17];
    const float* e_val_b2 = (const float*)d_in[18];
    const float* d_key_W1 = (const float*)d_in[19];
    const float* d_key_b1 = (const float*)d_in[20];
    const float* d_key_g  = (const float*)d_in[21];
    const float* d_key_be = (const float*)d_in[22];
    const float* d_key_W2 = (const float*)d_in[23];
    const float* d_key_b2 = (const float*)d_in[24];
    const float* d_dec_W1 = (const float*)d_in[25];
    const float* d_dec_b1 = (const float*)d_in[26];
    const float* d_dec_W2 = (const float*)d_in[27];
    const float* d_dec_b2 = (const float*)d_in[28];
    const float* d_size_W1= (const float*)d_in[29];
    const float* d_size_b1= (const float*)d_in[30];
    const float* d_size_g = (const float*)d_in[31];
    const float* d_size_be= (const float*)d_in[32];
    const float* d_size_W2= (const float*)d_in[33];
    const float* d_size_b2= (const float*)d_in[34];

    char* ws = (char*)d_ws;
    int*          starts  = (int*)         (ws + 0);
    unsigned int* maxmag  = (unsigned int*)(ws + 8448);
    int*          kidx    = (int*)         (ws + 8704);
    float*        mag     = (float*)       (ws + 270848);
    float*        enc_tbl = (float*)       (ws + 532992);
    float*        dec_tbl = (float*)       (ws + 666112);
    float*        z       = (float*)       (ws + 797184);
    int*          ndec    = (int*)         (ws + 4991488);
    int*          cnt     = (int*)         (ws + 4999680);
    int*          cntpad  = (int*)         (ws + 4999684);
    int*          rowmap  = (int*)         (ws + 5000192);
    ushort_t*     evW1t   = (ushort_t*)    (ws + 5524480);
    ushort_t*     evW2t   = (ushort_t*)    (ws + 5721088);
    ushort_t*     ddW1t   = (ushort_t*)    (ws + 6114304);
    ushort_t*     ddW2t   = (ushort_t*)    (ws + 6507520);
    ushort_t*     xb      = (ushort_t*)    (ws + 6704384);
    ushort_t*     Hb      = (ushort_t*)    (ws + 6704384 + 33554432);
    ushort_t*     Hd      = (ushort_t*)    (ws + 6704384);

    float* out_x = (float*)d_out;
    float* out_b = out_x + (size_t)NB * MAXNN * DIMX;
    float* out_m = out_b + NB * MAXNN;

    k_starts<<<dim3(9), dim3(256), 0, stream>>>(batch, starts, maxmag, cnt);
    k_mag<<<dim3(1024), dim3(256), 0, stream>>>(x, e_rank_W, e_rank_b, mag, maxmag, xb);
    k_rank<<<dim3(256), dim3(256), 0, stream>>>(batch, starts, mag, maxmag, kidx);
    k_table<<<dim3(65), dim3(512), 0, stream>>>(e_key_W1, e_key_b1, e_key_g, e_key_be,
                                                e_key_W2, e_key_b2, enc_tbl, MIDK, 64);
    k_table<<<dim3(64), dim3(512), 0, stream>>>(d_key_W1, d_key_b1, d_key_g, d_key_be,
                                                d_key_W2, d_key_b2, dec_tbl, MIDK, 64);
    k_card<<<dim3(4096), dim3(256), 0, stream>>>(starts, e_card_W, e_card_b, z);
    k_wt_all<<<dim3(2304), dim3(256), 0, stream>>>(e_val_W1, evW1t, e_val_W2, evW2t,
                                                   d_dec_W1, ddW1t, d_dec_W2, ddW2t);

    // E1 fused with LN+mish
    k_mm_e1f<<<dim3(512), dim3(512), 0, stream>>>(xb, evW1t, e_val_b1,
                                                  e_val_g, e_val_be, Hb);
    k_mm_e2<<<dim3(4, 512), dim3(256), 0, stream>>>(Hb, evW2t, e_val_b2, MIDV,
                                                    enc_tbl, kidx, batch, z);
    k_size<<<dim3(NB / 4), dim3(256), 0, stream>>>(z, d_size_W1, d_size_b1, d_size_g,
                                                   d_size_be, d_size_W2, d_size_b2, ndec);
    k_compact<<<dim3(8), dim3(256), 0, stream>>>(ndec, cnt, rowmap);
    k_pad<<<dim3(1), dim3(128), 0, stream>>>(cnt, cntpad, rowmap);
    hipMemsetAsync(out_x, 0, (size_t)NB * MAXNN * DIMX * sizeof(float), stream);
    k_mm_d1<<<dim3(3, 1024), dim3(256), 0, stream>>>(ddW1t, d_dec_b1, Hd, HIDN,
                                                     dec_tbl, z, rowmap, cntpad);
    k_mm_d2<<<dim3(2, 1024), dim3(256), 0, stream>>>(Hd, ddW2t, d_dec_b2, out_x, MIDD,
                                                     rowmap, cntpad);
    k_tail<<<dim3(512), dim3(256), 0, stream>>>(ndec, out_b, out_m);
}